// Round 1
// baseline (1043.019 us; speedup 1.0000x reference)
//
#include <hip/hip_runtime.h>
#include <hip/hip_bf16.h>

// Problem: B=16, N=4096, C=768, H=12, D=64
// x[16,4096,768] f32; w_qkv[768,2304] f32; w_proj[768,768] f32; b_proj[768] f32
// out[16,4096,768] f32

typedef __attribute__((ext_vector_type(8))) short short8_t;
typedef __attribute__((ext_vector_type(4))) float f32x4_t;

typedef __attribute__((address_space(1))) void as1_void;
typedef __attribute__((address_space(3))) void as3_void;

__device__ __forceinline__ void gload_lds16(const void* g, void* l) {
    __builtin_amdgcn_global_load_lds(
        (as1_void*)(unsigned long long)(g),
        (as3_void*)(unsigned long long)(l), 16, 0, 0);
}

__device__ __forceinline__ float gelu_exact(float x) {
    return 0.5f * x * (1.0f + erff(x * 0.7071067811865475f));
}

__device__ __forceinline__ unsigned short to_bf16(float f) {
    __hip_bfloat16 h = __float2bfloat16(f);
    return *reinterpret_cast<unsigned short*>(&h);
}

// ---------------- f32 -> bf16 convert (vectorized) ----------------
__global__ __launch_bounds__(256) void k_cvt_bf16(const float* __restrict__ in,
                                                  unsigned short* __restrict__ out,
                                                  long n) {
    long i = (long)blockIdx.x * blockDim.x + threadIdx.x;
    long stride = (long)gridDim.x * blockDim.x;
    for (long idx = i * 4; idx < n; idx += stride * 4) {
        float4 v = *(const float4*)(in + idx);
        ushort4 o;
        o.x = to_bf16(v.x); o.y = to_bf16(v.y); o.z = to_bf16(v.z); o.w = to_bf16(v.w);
        *(ushort4*)(out + idx) = o;
    }
}

// ---------------- transpose+convert w_qkv [768][2304] -> [2304][768] bf16 ----------------
__global__ __launch_bounds__(256) void k_wqkvT(const float* __restrict__ w,
                                               unsigned short* __restrict__ wT) {
    int idx = blockIdx.x * 256 + threadIdx.x;   // over 768*2304
    int r = idx / 2304, c = idx % 2304;
    wT[(size_t)c * 768 + r] = to_bf16(w[idx]);
}

// ---------------- GEMM C = A @ Bt^T  (A[M,K] bf16 lda; Bt[N,K] bf16 ldb=K) ----------------
// 128x128 tile, BK=32, 4 waves (2x2), 16x16x32 bf16 MFMA, global_load_lds staging.
template<bool GELU_EPI, bool BATCHED_B, bool BF16_OUT, bool BIAS>
__global__ __launch_bounds__(256)
void k_gemm_bt(const unsigned short* __restrict__ A, int lda,
               const unsigned short* __restrict__ Bt,
               void* __restrict__ Cout, int ldc,
               const float* __restrict__ bias,
               int tiles_n, int K) {
    __shared__ __attribute__((aligned(16))) unsigned short As[128 * 32];
    __shared__ __attribute__((aligned(16))) unsigned short Bs[128 * 32];

    const int bid = blockIdx.x;
    const int tn = bid % tiles_n, tm = bid / tiles_n;
    const int row0 = tm * 128;
    const int col0 = tn * 128;

    const unsigned short* Bb = Bt;
    if (BATCHED_B) Bb += (size_t)(row0 >> 12) * 768 * 768;  // batch = row0/4096, Bt per-batch [768][768]

    const int tid = threadIdx.x;
    const int lane = tid & 63;
    const int w = tid >> 6;
    const int wm = (w >> 1) * 64;
    const int wn = (w & 1) * 64;

    f32x4_t acc[4][4] = {};

    const int nkt = K >> 5;
    for (int kt = 0; kt < nkt; ++kt) {
        const int kofs = kt * 32;
        // stage A-tile [128][32] and B-tile [128][32]; 512 16B-chunks each-half, 2 per thread per matrix
#pragma unroll
        for (int i = 0; i < 2; ++i) {
            gload_lds16(A + (size_t)(row0 + i * 64 + (tid >> 2)) * lda + (tid & 3) * 8 + kofs,
                        As + (i * 256 + tid) * 8);
            gload_lds16(Bb + (size_t)(col0 + i * 64 + (tid >> 2)) * (size_t)K + (tid & 3) * 8 + kofs,
                        Bs + (i * 256 + tid) * 8);
        }
        __syncthreads();

        const int lr = lane & 15, lk = (lane >> 4) * 8;
        short8_t a[4], b[4];
#pragma unroll
        for (int mi = 0; mi < 4; ++mi)
            a[mi] = *(const short8_t*)(As + (wm + mi * 16 + lr) * 32 + lk);
#pragma unroll
        for (int nj = 0; nj < 4; ++nj)
            b[nj] = *(const short8_t*)(Bs + (wn + nj * 16 + lr) * 32 + lk);
#pragma unroll
        for (int mi = 0; mi < 4; ++mi)
#pragma unroll
            for (int nj = 0; nj < 4; ++nj)
                acc[mi][nj] = __builtin_amdgcn_mfma_f32_16x16x32_bf16(a[mi], b[nj], acc[mi][nj], 0, 0, 0);
        __syncthreads();
    }

    // epilogue: D layout col=lane&15, row=(lane>>4)*4+r
    const int rbase = row0 + wm + ((lane >> 4) << 2);
    const int cbase = col0 + wn + (lane & 15);
#pragma unroll
    for (int mi = 0; mi < 4; ++mi)
#pragma unroll
        for (int nj = 0; nj < 4; ++nj)
#pragma unroll
            for (int r = 0; r < 4; ++r) {
                int row = rbase + mi * 16 + r;
                int col = cbase + nj * 16;
                float v = acc[mi][nj][r];
                if (GELU_EPI) { if (col < 768) v = gelu_exact(v); }
                if (BIAS) v += bias[col];
                if (BF16_OUT)
                    ((unsigned short*)Cout)[(size_t)row * ldc + col] = to_bf16(v);
                else
                    ((float*)Cout)[(size_t)row * ldc + col] = v;
            }
}

// ---------------- kv partials: part[ch*192+bh][d][e] = sum_{n in chunk} k[n,d]*v[n,e] ----------------
// grid 1536 = 8 chunks * 192 (b,h); chunk covers 512 rows, staged 32/iter with LDS transpose.
__global__ __launch_bounds__(256) void k_kvpart(const unsigned short* __restrict__ qkv,
                                                float* __restrict__ part) {
    const int bid = blockIdx.x;
    const int ch = bid / 192, bh = bid % 192;
    const int b = bh / 12, h = bh % 12;
    const size_t rowbase = (size_t)b * 4096 + (size_t)ch * 512;
    const unsigned short* kptr = qkv + 768 + h * 64;
    const unsigned short* vptr = qkv + 1536 + h * 64;

    __shared__ __attribute__((aligned(16))) unsigned short kT[64 * 32];  // [d][n]
    __shared__ __attribute__((aligned(16))) unsigned short vT[64 * 32];  // [e][n]

    const int tid = threadIdx.x, lane = tid & 63, w = tid >> 6;
    const int d0 = (tid & 7) * 8;   // 8 consecutive d per thread
    const int nl = tid >> 3;        // 0..31 local row

    f32x4_t acc[4] = {};

    for (int it = 0; it < 16; ++it) {
        size_t grow = rowbase + it * 32 + nl;
        short8_t k8 = *(const short8_t*)(kptr + grow * 2304 + d0);
        short8_t v8 = *(const short8_t*)(vptr + grow * 2304 + d0);
        __syncthreads();   // previous iter's frag reads done before overwrite
#pragma unroll
        for (int j = 0; j < 8; ++j) {
            kT[(d0 + j) * 32 + nl] = (unsigned short)k8[j];
            vT[(d0 + j) * 32 + nl] = (unsigned short)v8[j];
        }
        __syncthreads();
        const int lr = lane & 15, lk = (lane >> 4) * 8;
        short8_t a = *(const short8_t*)(kT + (w * 16 + lr) * 32 + lk);   // A[d][n]
#pragma unroll
        for (int nj = 0; nj < 4; ++nj) {
            short8_t bf = *(const short8_t*)(vT + (nj * 16 + lr) * 32 + lk);  // B[n][e]
            acc[nj] = __builtin_amdgcn_mfma_f32_16x16x32_bf16(a, bf, acc[nj], 0, 0, 0);
        }
    }

    float* pout = part + (size_t)bid * 4096;
    const int rb = w * 16 + ((lane >> 4) << 2);
    const int cb = lane & 15;
#pragma unroll
    for (int nj = 0; nj < 4; ++nj)
#pragma unroll
        for (int r = 0; r < 4; ++r)
            pout[(rb + r) * 64 + nj * 16 + cb] = acc[nj][r];
}

// ---------------- reduce partials + scale + gelu, then M = gkv @ Wp_rows; store MT[b][c][h*64+d] bf16 ----------------
__global__ __launch_bounds__(256) void k_makeM(const float* __restrict__ part,
                                               const float* __restrict__ wproj,
                                               unsigned short* __restrict__ MT) {
    const int bh = blockIdx.x;           // 0..191
    const int b = bh / 12, h = bh % 12;
    __shared__ float gkv[4096];          // [d][e] f32
    const int tid = threadIdx.x;
    for (int i = tid; i < 4096; i += 256) {
        float s = 0.f;
#pragma unroll
        for (int ch = 0; ch < 8; ++ch) s += part[((size_t)ch * 192 + bh) * 4096 + i];
        s *= 0.125f;                     // SCALE = 64^-0.5
        gkv[i] = gelu_exact(s);
    }
    __syncthreads();
    for (int idx = tid; idx < 64 * 768; idx += 256) {
        int d = idx / 768, c = idx % 768;
        float acc = 0.f;
#pragma unroll 8
        for (int e = 0; e < 64; ++e)
            acc = fmaf(gkv[d * 64 + e], wproj[(h * 64 + e) * 768 + c], acc);
        MT[((size_t)b * 768 + c) * 768 + h * 64 + d] = to_bf16(acc);
    }
}

extern "C" void kernel_launch(void* const* d_in, const int* in_sizes, int n_in,
                              void* d_out, int out_size, void* d_ws, size_t ws_size,
                              hipStream_t stream) {
    const float* x      = (const float*)d_in[0];
    const float* w_qkv  = (const float*)d_in[1];
    const float* w_proj = (const float*)d_in[2];
    const float* b_proj = (const float*)d_in[3];
    float* out = (float*)d_out;
    char* ws = (char*)d_ws;

    // workspace layout (bytes)
    unsigned short* qkv_bf = (unsigned short*)(ws);               // 65536*2304*2 = 301,989,888
    unsigned short* wqkvT  = (unsigned short*)(ws + 301989888);   // 2304*768*2   =   3,538,944
    float*          part   = (float*)(ws + 305528832);            // 1536*4096*4  =  25,165,824
    unsigned short* MT     = (unsigned short*)(ws + 330694656);   // 16*768*768*2 =  18,874,368
    // xb (bf16 copy of x) lives in d_out (201 MB buffer, only 100 MB needed; dead before final GEMM)
    unsigned short* xb = (unsigned short*)d_out;

    // 1) convert x -> bf16
    k_cvt_bf16<<<2048, 256, 0, stream>>>(x, xb, 50331648L);
    // 2) transpose+convert w_qkv -> [2304][768] bf16
    k_wqkvT<<<6912, 256, 0, stream>>>(w_qkv, wqkvT);
    // 3) GEMM1: qkv_bf[65536][2304] = xb @ wqkvT^T, gelu applied to q columns (<768)
    k_gemm_bt<true, false, true, false><<<512 * 18, 256, 0, stream>>>(
        xb, 768, wqkvT, qkv_bf, 2304, nullptr, 18, 768);
    // 4) kv partials over 8 n-chunks
    k_kvpart<<<1536, 256, 0, stream>>>(qkv_bf, part);
    // 5) reduce + scale + gelu + fold w_proj -> MT[b][c][hd]
    k_makeM<<<192, 256, 0, stream>>>(part, w_proj, MT);
    // 6) GEMM2: out[65536][768] = gq(@qkv_bf cols 0..767) @ MT_b^T + b_proj
    k_gemm_bt<false, true, false, true><<<512 * 6, 256, 0, stream>>>(
        qkv_bf, 2304, MT, out, 768, b_proj, 6, 768);
}

// Round 2
// 853.505 us; speedup vs baseline: 1.2220x; 1.2220x over previous
//
#include <hip/hip_runtime.h>
#include <hip/hip_bf16.h>

// Problem: B=16, N=4096, C=768, H=12, D=64
// x[16,4096,768] f32; w_qkv[768,2304] f32; w_proj[768,768] f32; b_proj[768] f32
// out[16,4096,768] f32

typedef __attribute__((ext_vector_type(8))) short short8_t;
typedef __attribute__((ext_vector_type(4))) float f32x4_t;

typedef __attribute__((address_space(1))) void as1_void;
typedef __attribute__((address_space(3))) void as3_void;

__device__ __forceinline__ void gload_lds16(const void* g, void* l) {
    __builtin_amdgcn_global_load_lds(
        (as1_void*)(unsigned long long)(g),
        (as3_void*)(unsigned long long)(l), 16, 0, 0);
}

__device__ __forceinline__ float gelu_exact(float x) {
    return 0.5f * x * (1.0f + erff(x * 0.7071067811865475f));
}

__device__ __forceinline__ unsigned short to_bf16(float f) {
    __hip_bfloat16 h = __float2bfloat16(f);
    return *reinterpret_cast<unsigned short*>(&h);
}

// ---------------- f32 -> bf16 convert (vectorized) ----------------
__global__ __launch_bounds__(256) void k_cvt_bf16(const float* __restrict__ in,
                                                  unsigned short* __restrict__ out,
                                                  long n) {
    long i = (long)blockIdx.x * blockDim.x + threadIdx.x;
    long stride = (long)gridDim.x * blockDim.x;
    for (long idx = i * 4; idx < n; idx += stride * 4) {
        float4 v = *(const float4*)(in + idx);
        ushort4 o;
        o.x = to_bf16(v.x); o.y = to_bf16(v.y); o.z = to_bf16(v.z); o.w = to_bf16(v.w);
        *(ushort4*)(out + idx) = o;
    }
}

// ---------------- transpose+convert w_qkv [768][2304] -> [2304][768] bf16 ----------------
// Each thread gathers 8 f32 down a column (L2-resident, 7 MB) and writes 16B coalesced.
__global__ __launch_bounds__(256) void k_wqkvT(const float* __restrict__ w,
                                               unsigned short* __restrict__ wT) {
    int gid = blockIdx.x * 256 + threadIdx.x;       // 2304 * 96
    int c = gid / 96, rblk = gid % 96;
    int r0 = rblk * 8;
    short8_t o;
#pragma unroll
    for (int i = 0; i < 8; ++i)
        o[i] = (short)to_bf16(w[(size_t)(r0 + i) * 2304 + c]);
    *(short8_t*)(wT + (size_t)c * 768 + r0) = o;
}

// ================= 256x256 8-phase GEMM: C = A @ Bt^T =================
// A[M,K] bf16 (lda), Bt[N,K] bf16 (ldb==K). 512 thr = 8 waves (2M x 4N).
// BK=64, double-buffered 2-K-tiles-in-flight, LDS 128 KiB, XOR-swizzled
// staging (pre-swizzled global source, linear LDS dest), counted vmcnt.
template<bool GELU_EPI, bool BATCHED_B, bool BF16_OUT, bool BIAS>
__global__ __launch_bounds__(512, 2)
void k_gemm256(const unsigned short* __restrict__ A, int lda,
               const unsigned short* __restrict__ Bt, int ldb,
               void* __restrict__ Cout, int ldc,
               const float* __restrict__ bias,
               int tiles_n, int K) {
    // [mat][dbuf][half][128 rows][64 cols] bf16 ; 4*2*16KB = 128 KiB
    __shared__ __attribute__((aligned(16))) unsigned short lds[2][2][2][128 * 64];

    const int nwg = gridDim.x;
    int bid = blockIdx.x;
    // XCD-aware bijective swizzle (nwg % 8 == 0 for both launches)
    bid = (bid & 7) * (nwg >> 3) + (bid >> 3);

    const int tn = bid % tiles_n, tm = bid / tiles_n;
    const int row0 = tm * 256, col0 = tn * 256;

    const unsigned short* Bb = Bt;
    if (BATCHED_B) Bb += (size_t)(row0 >> 12) * 768 * 768;

    const int tid = threadIdx.x;
    const int lane = tid & 63;
    const int w = tid >> 6;
    const int wm = w >> 2;        // 0..1 : row half (128 rows)
    const int wn = w & 3;         // 0..3 : col quarter (64 cols)
    const int lr = lane & 15, lg = lane >> 4;

    // staging geometry: half-tile = 1024 x 16B chunks; 2 loads/thread.
    // LDS dest linear chunk c; source pre-swizzled: row=c>>3, kchunk=(c&7)^(row&7)
    const int c0 = tid, c1 = 512 + tid;
    const int sr0 = c0 >> 3, sk0 = (c0 & 7) ^ (sr0 & 7);
    const int sr1 = c1 >> 3, sk1 = (c1 & 7) ^ (sr1 & 7);

    auto stageA = [&](int buf, int half, int kt) {
        const unsigned short* base = A + (size_t)(row0 + half * 128) * lda + kt * 64;
        gload_lds16(base + (size_t)sr0 * lda + sk0 * 8, &lds[0][buf][half][c0 * 8]);
        gload_lds16(base + (size_t)sr1 * lda + sk1 * 8, &lds[0][buf][half][c1 * 8]);
    };
    auto stageB = [&](int buf, int half, int kt) {
        const unsigned short* base = Bb + (size_t)(col0 + half * 128) * ldb + kt * 64;
        gload_lds16(base + (size_t)sr0 * ldb + sk0 * 8, &lds[1][buf][half][c0 * 8]);
        gload_lds16(base + (size_t)sr1 * ldb + sk1 * 8, &lds[1][buf][half][c1 * 8]);
    };
    // swizzled ds_read of one b128 fragment
    auto ldA = [&](int buf, int mi, int ks) -> short8_t {
        int row = mi * 16 + lr;
        int kc = (ks * 4 + lg) ^ (row & 7);
        return *(const short8_t*)&lds[0][buf][wm][row * 64 + kc * 8];
    };
    auto ldB = [&](int buf, int nj, int ks) -> short8_t {
        int row = wn * 64 + nj * 16 + lr;          // 0..255
        int half = row >> 7, rl = row & 127;
        int kc = (ks * 4 + lg) ^ (rl & 7);
        return *(const short8_t*)&lds[1][buf][half][rl * 64 + kc * 8];
    };

    f32x4_t acc[8][4] = {};
    short8_t bfrag[4][2];

#define FENCE asm volatile("" ::: "memory")
#define PHASE(q, buf, STAGE_STMT, VM_STMT)                                      \
    {                                                                           \
        short8_t afr[2][2];                                                     \
        if (q == 0) {                                                           \
            _Pragma("unroll") for (int nj = 0; nj < 4; ++nj)                    \
                _Pragma("unroll") for (int ks = 0; ks < 2; ++ks)                \
                    bfrag[nj][ks] = ldB(buf, nj, ks);                           \
        }                                                                       \
        _Pragma("unroll") for (int mi = 0; mi < 2; ++mi)                        \
            _Pragma("unroll") for (int ks = 0; ks < 2; ++ks)                    \
                afr[mi][ks] = ldA(buf, 2 * q + mi, ks);                         \
        STAGE_STMT;                                                             \
        VM_STMT;                                                                \
        FENCE;                                                                  \
        __builtin_amdgcn_s_barrier();                                           \
        FENCE;                                                                  \
        __builtin_amdgcn_s_setprio(1);                                          \
        _Pragma("unroll") for (int mi = 0; mi < 2; ++mi)                        \
            _Pragma("unroll") for (int ks = 0; ks < 2; ++ks)                    \
                _Pragma("unroll") for (int nj = 0; nj < 4; ++nj)                \
                    acc[2 * q + mi][nj] = __builtin_amdgcn_mfma_f32_16x16x32_bf16( \
                        afr[mi][ks], bfrag[nj][ks], acc[2 * q + mi][nj], 0, 0, 0); \
        __builtin_amdgcn_s_setprio(0);                                          \
        FENCE;                                                                  \
        __builtin_amdgcn_s_barrier();                                           \
        FENCE;                                                                  \
    }

    const int nt = K >> 6;          // K-tiles (12 for K=768)
    const int niter = nt >> 1;      // 6

    // prologue: tile0 full into buf0; tile1 B-halves into buf1 (A of tile1 staged at p1/p2)
    stageA(0, 0, 0); stageA(0, 1, 0); stageB(0, 0, 0); stageB(0, 1, 0);
    stageB(1, 0, 1); stageB(1, 1, 1);
    asm volatile("s_waitcnt vmcnt(4)" ::: "memory");   // tile0's 8 loads landed
    __builtin_amdgcn_s_barrier();
    FENCE;

    for (int it = 0; it < niter; ++it) {
        const int t1 = 2 * it + 1;
        const int tA = (2 * it + 2 < nt) ? 2 * it + 2 : 0;   // clamped prefetch
        const int tB = (2 * it + 3 < nt) ? 2 * it + 3 : 0;
        // phases 1-4: compute tile 2it from buf0
        PHASE(0, 0, stageA(1, 0, t1), (void)0);
        PHASE(1, 0, stageA(1, 1, t1), (void)0);
        PHASE(2, 0, stageB(0, 0, tA), (void)0);
        PHASE(3, 0, stageB(0, 1, tA), asm volatile("s_waitcnt vmcnt(4)" ::: "memory"));
        // phases 5-8: compute tile 2it+1 from buf1
        PHASE(0, 1, stageA(0, 0, tA), (void)0);
        PHASE(1, 1, stageA(0, 1, tA), (void)0);
        PHASE(2, 1, stageB(1, 0, tB), (void)0);
        PHASE(3, 1, stageB(1, 1, tB), asm volatile("s_waitcnt vmcnt(4)" ::: "memory"));
    }
    asm volatile("s_waitcnt vmcnt(0)" ::: "memory");   // drain stray prefetches
#undef PHASE
#undef FENCE

    // epilogue: D layout col=lane&15, row=(lane>>4)*4+r
    const int rbase = row0 + wm * 128 + (lg << 2);
    const int cbase = col0 + wn * 64 + lr;
#pragma unroll
    for (int mi = 0; mi < 8; ++mi)
#pragma unroll
        for (int nj = 0; nj < 4; ++nj)
#pragma unroll
            for (int r = 0; r < 4; ++r) {
                int row = rbase + mi * 16 + r;
                int col = cbase + nj * 16;
                float v = acc[mi][nj][r];
                if (GELU_EPI) { if (col < 768) v = gelu_exact(v); }
                if (BIAS) v += bias[col];
                if (BF16_OUT)
                    ((unsigned short*)Cout)[(size_t)row * ldc + col] = to_bf16(v);
                else
                    ((float*)Cout)[(size_t)row * ldc + col] = v;
            }
}

// ---------------- kv partials: part[ch*192+bh][d][e] = sum_{n in chunk} k[n,d]*v[n,e] ----------------
// 64 rows/iter; transposed LDS with d-dependent XOR swizzle -> conflict-free-ish.
__global__ __launch_bounds__(256) void k_kvpart(const unsigned short* __restrict__ qkv,
                                                float* __restrict__ part) {
    const int bid = blockIdx.x;
    const int ch = bid / 192, bh = bid % 192;
    const int b = bh / 12, h = bh % 12;
    const size_t rowbase = (size_t)b * 4096 + (size_t)ch * 512;
    const unsigned short* kptr = qkv + 768 + h * 64;
    const unsigned short* vptr = qkv + 1536 + h * 64;

    __shared__ __attribute__((aligned(16))) unsigned short kT[64 * 64];  // (d,n) at d*64 + (n ^ swz(d)<<3)
    __shared__ __attribute__((aligned(16))) unsigned short vT[64 * 64];

    const int tid = threadIdx.x, lane = tid & 63, w = tid >> 6;
    const int np = tid >> 3;            // 0..31 -> rows 2np, 2np+1
    const int g = tid & 7;              // d-group: d = g*8 + j

    f32x4_t acc[4] = {};

    for (int it = 0; it < 8; ++it) {
        const size_t r0 = (rowbase + it * 64 + 2 * np) * 2304;
        short8_t k0 = *(const short8_t*)(kptr + r0 + g * 8);
        short8_t k1 = *(const short8_t*)(kptr + r0 + 2304 + g * 8);
        short8_t v0 = *(const short8_t*)(vptr + r0 + g * 8);
        short8_t v1 = *(const short8_t*)(vptr + r0 + 2304 + g * 8);
        __syncthreads();   // previous iter's reads done before overwrite
#pragma unroll
        for (int j = 0; j < 8; ++j) {
            const int d = g * 8 + j;
            const int e = d * 64 + ((2 * np) ^ (((d ^ (d >> 3)) & 7) << 3));
            *(unsigned int*)(kT + e) =
                (unsigned int)(unsigned short)k0[j] | ((unsigned int)(unsigned short)k1[j] << 16);
            *(unsigned int*)(vT + e) =
                (unsigned int)(unsigned short)v0[j] | ((unsigned int)(unsigned short)v1[j] << 16);
        }
        __syncthreads();
        const int lr = lane & 15, lg = lane >> 4;
#pragma unroll
        for (int ks = 0; ks < 2; ++ks) {
            const int d = w * 16 + lr;
            short8_t a = *(const short8_t*)(kT + d * 64 +
                (((ks * 4 + lg) ^ ((d ^ (d >> 3)) & 7)) << 3));
#pragma unroll
            for (int nj = 0; nj < 4; ++nj) {
                const int e2 = nj * 16 + lr;
                short8_t bf = *(const short8_t*)(vT + e2 * 64 +
                    (((ks * 4 + lg) ^ ((e2 ^ (e2 >> 3)) & 7)) << 3));
                acc[nj] = __builtin_amdgcn_mfma_f32_16x16x32_bf16(a, bf, acc[nj], 0, 0, 0);
            }
        }
    }

    float* pout = part + (size_t)bid * 4096;
    const int rb = w * 16 + ((lane >> 4) << 2);
    const int cb = lane & 15;
#pragma unroll
    for (int nj = 0; nj < 4; ++nj)
#pragma unroll
        for (int r = 0; r < 4; ++r)
            pout[(rb + r) * 64 + nj * 16 + cb] = acc[nj][r];
}

// ---------------- reduce partials + scale + gelu, then M = gkv @ Wp_rows; store MT[b][c][h*64+d] bf16 ----------------
__global__ __launch_bounds__(256) void k_makeM(const float* __restrict__ part,
                                               const float* __restrict__ wproj,
                                               unsigned short* __restrict__ MT) {
    const int bh = blockIdx.x;           // 0..191
    const int b = bh / 12, h = bh % 12;
    __shared__ float gkv[4096];          // [d][e] f32
    const int tid = threadIdx.x;
    for (int i = tid; i < 4096; i += 256) {
        float s = 0.f;
#pragma unroll
        for (int ch = 0; ch < 8; ++ch) s += part[((size_t)ch * 192 + bh) * 4096 + i];
        s *= 0.125f;                     // SCALE = 64^-0.5
        gkv[i] = gelu_exact(s);
    }
    __syncthreads();
    for (int idx = tid; idx < 64 * 768; idx += 256) {
        int d = idx / 768, c = idx % 768;
        float acc = 0.f;
#pragma unroll 8
        for (int e = 0; e < 64; ++e)
            acc = fmaf(gkv[d * 64 + e], wproj[(h * 64 + e) * 768 + c], acc);
        MT[((size_t)b * 768 + c) * 768 + h * 64 + d] = to_bf16(acc);
    }
}

extern "C" void kernel_launch(void* const* d_in, const int* in_sizes, int n_in,
                              void* d_out, int out_size, void* d_ws, size_t ws_size,
                              hipStream_t stream) {
    const float* x      = (const float*)d_in[0];
    const float* w_qkv  = (const float*)d_in[1];
    const float* w_proj = (const float*)d_in[2];
    const float* b_proj = (const float*)d_in[3];
    float* out = (float*)d_out;
    char* ws = (char*)d_ws;

    // workspace layout (bytes)
    unsigned short* qkv_bf = (unsigned short*)(ws);               // 65536*2304*2 = 301,989,888
    unsigned short* wqkvT  = (unsigned short*)(ws + 301989888);   // 2304*768*2   =   3,538,944
    float*          part   = (float*)(ws + 305528832);            // 1536*4096*4  =  25,165,824
    unsigned short* MT     = (unsigned short*)(ws + 330694656);   // 16*768*768*2 =  18,874,368
    // xb (bf16 copy of x) lives in d_out (201 MB buffer, dead before final GEMM)
    unsigned short* xb = (unsigned short*)d_out;

    // 1) convert x -> bf16
    k_cvt_bf16<<<2048, 256, 0, stream>>>(x, xb, 50331648L);
    // 2) transpose+convert w_qkv -> [2304][768] bf16
    k_wqkvT<<<864, 256, 0, stream>>>(w_qkv, wqkvT);
    // 3) GEMM1: qkv_bf[65536][2304] = xb @ wqkvT^T, gelu on q columns (<768); 256x9 tiles
    k_gemm256<true, false, true, false><<<2304, 512, 0, stream>>>(
        xb, 768, wqkvT, 768, qkv_bf, 2304, nullptr, 9, 768);
    // 4) kv partials over 8 n-chunks
    k_kvpart<<<1536, 256, 0, stream>>>(qkv_bf, part);
    // 5) reduce + scale + gelu + fold w_proj -> MT[b][c][hd]
    k_makeM<<<192, 256, 0, stream>>>(part, w_proj, MT);
    // 6) GEMM2: out[65536][768] = gelu(q) @ MT_b^T + b_proj; 256x3 tiles
    k_gemm256<false, true, false, true><<<768, 512, 0, stream>>>(
        qkv_bf, 2304, MT, 768, out, 768, b_proj, 3, 768);
}

// Round 3
// 515.854 us; speedup vs baseline: 2.0219x; 1.6545x over previous
//
#include <hip/hip_runtime.h>
#include <hip/hip_bf16.h>

// Problem: B=16, N=4096, C=768, H=12, D=64
// x[16,4096,768] f32; w_qkv[768,2304] f32; w_proj[768,768] f32; b_proj[768] f32
// out[16,4096,768] f32

typedef __attribute__((ext_vector_type(8))) short short8_t;
typedef __attribute__((ext_vector_type(4))) float f32x4_t;

typedef __attribute__((address_space(1))) void as1_void;
typedef __attribute__((address_space(3))) void as3_void;

__device__ __forceinline__ void gload_lds16(const void* g, void* l) {
    __builtin_amdgcn_global_load_lds(
        (as1_void*)(unsigned long long)(g),
        (as3_void*)(unsigned long long)(l), 16, 0, 0);
}

__device__ __forceinline__ float gelu_exact(float x) {
    return 0.5f * x * (1.0f + erff(x * 0.7071067811865475f));
}

__device__ __forceinline__ unsigned short to_bf16(float f) {
    __hip_bfloat16 h = __float2bfloat16(f);
    return *reinterpret_cast<unsigned short*>(&h);
}

// ---------------- f32 -> bf16 convert (vectorized) ----------------
__global__ __launch_bounds__(256) void k_cvt_bf16(const float* __restrict__ in,
                                                  unsigned short* __restrict__ out,
                                                  long n) {
    long i = (long)blockIdx.x * blockDim.x + threadIdx.x;
    long stride = (long)gridDim.x * blockDim.x;
    for (long idx = i * 4; idx < n; idx += stride * 4) {
        float4 v = *(const float4*)(in + idx);
        ushort4 o;
        o.x = to_bf16(v.x); o.y = to_bf16(v.y); o.z = to_bf16(v.z); o.w = to_bf16(v.w);
        *(ushort4*)(out + idx) = o;
    }
}

// ---------------- transpose+convert w_qkv [768][2304] -> [2304][768] bf16 ----------------
__global__ __launch_bounds__(256) void k_wqkvT(const float* __restrict__ w,
                                               unsigned short* __restrict__ wT) {
    int gid = blockIdx.x * 256 + threadIdx.x;       // 2304 * 96
    int c = gid / 96, rblk = gid % 96;
    int r0 = rblk * 8;
    short8_t o;
#pragma unroll
    for (int i = 0; i < 8; ++i)
        o[i] = (short)to_bf16(w[(size_t)(r0 + i) * 2304 + c]);
    *(short8_t*)(wT + (size_t)c * 768 + r0) = o;
}

// ---------------- transpose+convert w_proj [768][768] -> wpT[c][r] bf16 ----------------
__global__ __launch_bounds__(256) void k_wprojT(const float* __restrict__ w,
                                                unsigned short* __restrict__ wT) {
    int gid = blockIdx.x * 256 + threadIdx.x;       // 768 * 96
    int c = gid / 96, rblk = gid % 96;
    int r0 = rblk * 8;
    short8_t o;
#pragma unroll
    for (int i = 0; i < 8; ++i)
        o[i] = (short)to_bf16(w[(size_t)(r0 + i) * 768 + c]);
    *(short8_t*)(wT + (size_t)c * 768 + r0) = o;
}

// ================= 256x256 8-phase GEMM: C = A @ Bt^T =================
template<bool GELU_EPI, bool BATCHED_B, bool BF16_OUT, bool BIAS>
__global__ __launch_bounds__(512, 2)
void k_gemm256(const unsigned short* __restrict__ A, int lda,
               const unsigned short* __restrict__ Bt, int ldb,
               void* __restrict__ Cout, int ldc,
               const float* __restrict__ bias,
               int tiles_n, int K) {
    __shared__ __attribute__((aligned(16))) unsigned short lds[2][2][2][128 * 64];

    const int nwg = gridDim.x;
    int bid = blockIdx.x;
    bid = (bid & 7) * (nwg >> 3) + (bid >> 3);

    const int tn = bid % tiles_n, tm = bid / tiles_n;
    const int row0 = tm * 256, col0 = tn * 256;

    const unsigned short* Bb = Bt;
    if (BATCHED_B) Bb += (size_t)(row0 >> 12) * 768 * 768;

    const int tid = threadIdx.x;
    const int lane = tid & 63;
    const int w = tid >> 6;
    const int wm = w >> 2;
    const int wn = w & 3;
    const int lr = lane & 15, lg = lane >> 4;

    const int c0 = tid, c1 = 512 + tid;
    const int sr0 = c0 >> 3, sk0 = (c0 & 7) ^ (sr0 & 7);
    const int sr1 = c1 >> 3, sk1 = (c1 & 7) ^ (sr1 & 7);

    auto stageA = [&](int buf, int half, int kt) {
        const unsigned short* base = A + (size_t)(row0 + half * 128) * lda + kt * 64;
        gload_lds16(base + (size_t)sr0 * lda + sk0 * 8, &lds[0][buf][half][c0 * 8]);
        gload_lds16(base + (size_t)sr1 * lda + sk1 * 8, &lds[0][buf][half][c1 * 8]);
    };
    auto stageB = [&](int buf, int half, int kt) {
        const unsigned short* base = Bb + (size_t)(col0 + half * 128) * ldb + kt * 64;
        gload_lds16(base + (size_t)sr0 * ldb + sk0 * 8, &lds[1][buf][half][c0 * 8]);
        gload_lds16(base + (size_t)sr1 * ldb + sk1 * 8, &lds[1][buf][half][c1 * 8]);
    };
    auto ldA = [&](int buf, int mi, int ks) -> short8_t {
        int row = mi * 16 + lr;
        int kc = (ks * 4 + lg) ^ (row & 7);
        return *(const short8_t*)&lds[0][buf][wm][row * 64 + kc * 8];
    };
    auto ldB = [&](int buf, int nj, int ks) -> short8_t {
        int row = wn * 64 + nj * 16 + lr;
        int half = row >> 7, rl = row & 127;
        int kc = (ks * 4 + lg) ^ (rl & 7);
        return *(const short8_t*)&lds[1][buf][half][rl * 64 + kc * 8];
    };

    f32x4_t acc[8][4] = {};
    short8_t bfrag[4][2];

#define FENCE asm volatile("" ::: "memory")
#define PHASE(q, buf, STAGE_STMT, VM_STMT)                                      \
    {                                                                           \
        short8_t afr[2][2];                                                     \
        if (q == 0) {                                                           \
            _Pragma("unroll") for (int nj = 0; nj < 4; ++nj)                    \
                _Pragma("unroll") for (int ks = 0; ks < 2; ++ks)                \
                    bfrag[nj][ks] = ldB(buf, nj, ks);                           \
        }                                                                       \
        _Pragma("unroll") for (int mi = 0; mi < 2; ++mi)                        \
            _Pragma("unroll") for (int ks = 0; ks < 2; ++ks)                    \
                afr[mi][ks] = ldA(buf, 2 * q + mi, ks);                         \
        STAGE_STMT;                                                             \
        VM_STMT;                                                                \
        FENCE;                                                                  \
        __builtin_amdgcn_s_barrier();                                           \
        FENCE;                                                                  \
        __builtin_amdgcn_s_setprio(1);                                          \
        _Pragma("unroll") for (int mi = 0; mi < 2; ++mi)                        \
            _Pragma("unroll") for (int ks = 0; ks < 2; ++ks)                    \
                _Pragma("unroll") for (int nj = 0; nj < 4; ++nj)                \
                    acc[2 * q + mi][nj] = __builtin_amdgcn_mfma_f32_16x16x32_bf16( \
                        afr[mi][ks], bfrag[nj][ks], acc[2 * q + mi][nj], 0, 0, 0); \
        __builtin_amdgcn_s_setprio(0);                                          \
        FENCE;                                                                  \
        __builtin_amdgcn_s_barrier();                                           \
        FENCE;                                                                  \
    }

    const int nt = K >> 6;
    const int niter = nt >> 1;

    stageA(0, 0, 0); stageA(0, 1, 0); stageB(0, 0, 0); stageB(0, 1, 0);
    stageB(1, 0, 1); stageB(1, 1, 1);
    asm volatile("s_waitcnt vmcnt(4)" ::: "memory");
    __builtin_amdgcn_s_barrier();
    FENCE;

    for (int it = 0; it < niter; ++it) {
        const int t1 = 2 * it + 1;
        const int tA = (2 * it + 2 < nt) ? 2 * it + 2 : 0;
        const int tB = (2 * it + 3 < nt) ? 2 * it + 3 : 0;
        PHASE(0, 0, stageA(1, 0, t1), (void)0);
        PHASE(1, 0, stageA(1, 1, t1), (void)0);
        PHASE(2, 0, stageB(0, 0, tA), (void)0);
        PHASE(3, 0, stageB(0, 1, tA), asm volatile("s_waitcnt vmcnt(4)" ::: "memory"));
        PHASE(0, 1, stageA(0, 0, tA), (void)0);
        PHASE(1, 1, stageA(0, 1, tA), (void)0);
        PHASE(2, 1, stageB(1, 0, tB), (void)0);
        PHASE(3, 1, stageB(1, 1, tB), asm volatile("s_waitcnt vmcnt(4)" ::: "memory"));
    }
    asm volatile("s_waitcnt vmcnt(0)" ::: "memory");
#undef PHASE
#undef FENCE

    const int rbase = row0 + wm * 128 + (lg << 2);
    const int cbase = col0 + wn * 64 + lr;
#pragma unroll
    for (int mi = 0; mi < 8; ++mi)
#pragma unroll
        for (int nj = 0; nj < 4; ++nj)
#pragma unroll
            for (int r = 0; r < 4; ++r) {
                int row = rbase + mi * 16 + r;
                int col = cbase + nj * 16;
                float v = acc[mi][nj][r];
                if (GELU_EPI) { if (col < 768) v = gelu_exact(v); }
                if (BIAS) v += bias[col];
                if (BF16_OUT)
                    ((unsigned short*)Cout)[(size_t)row * ldc + col] = to_bf16(v);
                else
                    ((float*)Cout)[(size_t)row * ldc + col] = v;
            }
}

// ---------------- kv partials: part[ch*192+bh][d][e] = sum_{n in chunk} k[n,d]*v[n,e] ----------------
__global__ __launch_bounds__(256) void k_kvpart(const unsigned short* __restrict__ qkv,
                                                float* __restrict__ part) {
    const int bid = blockIdx.x;
    const int ch = bid / 192, bh = bid % 192;
    const int b = bh / 12, h = bh % 12;
    const size_t rowbase = (size_t)b * 4096 + (size_t)ch * 512;
    const unsigned short* kptr = qkv + 768 + h * 64;
    const unsigned short* vptr = qkv + 1536 + h * 64;

    __shared__ __attribute__((aligned(16))) unsigned short kT[64 * 64];
    __shared__ __attribute__((aligned(16))) unsigned short vT[64 * 64];

    const int tid = threadIdx.x, lane = tid & 63, w = tid >> 6;
    const int np = tid >> 3;
    const int g = tid & 7;

    f32x4_t acc[4] = {};

    for (int it = 0; it < 8; ++it) {
        const size_t r0 = (rowbase + it * 64 + 2 * np) * 2304;
        short8_t k0 = *(const short8_t*)(kptr + r0 + g * 8);
        short8_t k1 = *(const short8_t*)(kptr + r0 + 2304 + g * 8);
        short8_t v0 = *(const short8_t*)(vptr + r0 + g * 8);
        short8_t v1 = *(const short8_t*)(vptr + r0 + 2304 + g * 8);
        __syncthreads();
#pragma unroll
        for (int j = 0; j < 8; ++j) {
            const int d = g * 8 + j;
            const int e = d * 64 + ((2 * np) ^ (((d ^ (d >> 3)) & 7) << 3));
            *(unsigned int*)(kT + e) =
                (unsigned int)(unsigned short)k0[j] | ((unsigned int)(unsigned short)k1[j] << 16);
            *(unsigned int*)(vT + e) =
                (unsigned int)(unsigned short)v0[j] | ((unsigned int)(unsigned short)v1[j] << 16);
        }
        __syncthreads();
        const int lr = lane & 15, lg = lane >> 4;
#pragma unroll
        for (int ks = 0; ks < 2; ++ks) {
            const int d = w * 16 + lr;
            short8_t a = *(const short8_t*)(kT + d * 64 +
                (((ks * 4 + lg) ^ ((d ^ (d >> 3)) & 7)) << 3));
#pragma unroll
            for (int nj = 0; nj < 4; ++nj) {
                const int e2 = nj * 16 + lr;
                short8_t bf = *(const short8_t*)(vT + e2 * 64 +
                    (((ks * 4 + lg) ^ ((e2 ^ (e2 >> 3)) & 7)) << 3));
                acc[nj] = __builtin_amdgcn_mfma_f32_16x16x32_bf16(a, bf, acc[nj], 0, 0, 0);
            }
        }
    }

    float* pout = part + (size_t)bid * 4096;
    const int rb = w * 16 + ((lane >> 4) << 2);
    const int cb = lane & 15;
#pragma unroll
    for (int nj = 0; nj < 4; ++nj)
#pragma unroll
        for (int r = 0; r < 4; ++r)
            pout[(rb + r) * 64 + nj * 16 + cb] = acc[nj][r];
}

// ---------------- reduce partials + scale + gelu -> gkvb bf16 [bh][64][64] ----------------
__global__ __launch_bounds__(256) void k_gkv(const float* __restrict__ part,
                                             unsigned short* __restrict__ gkvb) {
    const int bh = blockIdx.x;           // 0..191
    const int tid = threadIdx.x;
    const float* p0 = part + (size_t)bh * 4096 + tid * 16;
    float f[16];
#pragma unroll
    for (int j = 0; j < 16; ++j) f[j] = 0.f;
#pragma unroll
    for (int ch = 0; ch < 8; ++ch) {
        const float* p = p0 + (size_t)ch * 192 * 4096;
#pragma unroll
        for (int j4 = 0; j4 < 4; ++j4) {
            float4 v = *(const float4*)(p + j4 * 4);
            f[j4 * 4 + 0] += v.x; f[j4 * 4 + 1] += v.y;
            f[j4 * 4 + 2] += v.z; f[j4 * 4 + 3] += v.w;
        }
    }
    short8_t o0, o1;
#pragma unroll
    for (int j = 0; j < 8; ++j) {
        o0[j] = (short)to_bf16(gelu_exact(f[j] * 0.125f));
        o1[j] = (short)to_bf16(gelu_exact(f[8 + j] * 0.125f));
    }
    unsigned short* dst = gkvb + (size_t)bh * 4096 + tid * 16;
    *(short8_t*)(dst) = o0;
    *(short8_t*)(dst + 8) = o1;
}

// ---------------- M[d][c] = sum_e gkv[d][e]*wproj[h*64+e][c], stored as MT[b][c][hd] bf16 ----------------
// grid = 192 bh * 3 ctiles. MFMA 64x256x64 per block; full-line epilogue via LDS repack.
__global__ __launch_bounds__(256) void k_M(const unsigned short* __restrict__ gkvb,
                                           const unsigned short* __restrict__ wpT,
                                           unsigned short* __restrict__ MT) {
    __shared__ __attribute__((aligned(16))) unsigned short As[64 * 64];
    __shared__ __attribute__((aligned(16))) unsigned short Bs[256 * 64];

    const int bid = blockIdx.x;
    const int bh = bid / 3, ct = bid % 3;
    const int b = bh / 12, h = bh % 12;
    const int c0 = ct * 256;
    const int tid = threadIdx.x, lane = tid & 63, w = tid >> 6;
    const int lr = lane & 15, lg = lane >> 4;

    // reg-stage with XOR-swizzled LDS writes (both-sides swizzle)
    short8_t ra[2], rb[8];
#pragma unroll
    for (int i = 0; i < 2; ++i) {
        int ch = i * 256 + tid, row = ch >> 3, kc = ch & 7;
        ra[i] = *(const short8_t*)(gkvb + (size_t)bh * 4096 + row * 64 + kc * 8);
    }
#pragma unroll
    for (int i = 0; i < 8; ++i) {
        int ch = i * 256 + tid, row = ch >> 3, kc = ch & 7;
        rb[i] = *(const short8_t*)(wpT + (size_t)(c0 + row) * 768 + h * 64 + kc * 8);
    }
#pragma unroll
    for (int i = 0; i < 2; ++i) {
        int ch = i * 256 + tid, row = ch >> 3, kc = ch & 7;
        *(short8_t*)(As + row * 64 + ((kc ^ (row & 7)) * 8)) = ra[i];
    }
#pragma unroll
    for (int i = 0; i < 8; ++i) {
        int ch = i * 256 + tid, row = ch >> 3, kc = ch & 7;
        *(short8_t*)(Bs + row * 64 + ((kc ^ (row & 7)) * 8)) = rb[i];
    }
    __syncthreads();

    f32x4_t acc[4][4] = {};
#pragma unroll
    for (int ks = 0; ks < 2; ++ks) {
        short8_t a[4], bfr[4];
#pragma unroll
        for (int mi = 0; mi < 4; ++mi) {
            int row = mi * 16 + lr;
            a[mi] = *(const short8_t*)(As + row * 64 + (((ks * 4 + lg) ^ (row & 7)) * 8));
        }
#pragma unroll
        for (int nj = 0; nj < 4; ++nj) {
            int row = w * 64 + nj * 16 + lr;
            bfr[nj] = *(const short8_t*)(Bs + row * 64 + (((ks * 4 + lg) ^ (row & 7)) * 8));
        }
#pragma unroll
        for (int mi = 0; mi < 4; ++mi)
#pragma unroll
            for (int nj = 0; nj < 4; ++nj)
                acc[mi][nj] = __builtin_amdgcn_mfma_f32_16x16x32_bf16(a[mi], bfr[nj], acc[mi][nj], 0, 0, 0);
    }
    __syncthreads();   // Bs reads done; safe to reuse as output staging

    // repack: out[c_local][d] bf16 in Bs
#pragma unroll
    for (int mi = 0; mi < 4; ++mi)
#pragma unroll
        for (int nj = 0; nj < 4; ++nj) {
            unsigned int w0 = (unsigned int)to_bf16(acc[mi][nj][0]) |
                              ((unsigned int)to_bf16(acc[mi][nj][1]) << 16);
            unsigned int w1 = (unsigned int)to_bf16(acc[mi][nj][2]) |
                              ((unsigned int)to_bf16(acc[mi][nj][3]) << 16);
            uint2 pk; pk.x = w0; pk.y = w1;
            *(uint2*)(Bs + (w * 64 + nj * 16 + lr) * 64 + mi * 16 + lg * 4) = pk;
        }
    __syncthreads();
    // full-line stores: 8 chunks/thread, each 16B; consecutive lanes cover contiguous 128B runs
#pragma unroll
    for (int i = 0; i < 8; ++i) {
        int ch = i * 256 + tid, cl = ch >> 3, dk = ch & 7;
        short8_t v = *(const short8_t*)(Bs + cl * 64 + dk * 8);
        *(short8_t*)(MT + ((size_t)(b * 768) + c0 + cl) * 768 + h * 64 + dk * 8) = v;
    }
}

extern "C" void kernel_launch(void* const* d_in, const int* in_sizes, int n_in,
                              void* d_out, int out_size, void* d_ws, size_t ws_size,
                              hipStream_t stream) {
    const float* x      = (const float*)d_in[0];
    const float* w_qkv  = (const float*)d_in[1];
    const float* w_proj = (const float*)d_in[2];
    const float* b_proj = (const float*)d_in[3];
    float* out = (float*)d_out;
    char* ws = (char*)d_ws;

    // workspace layout (bytes)
    unsigned short* qkv_bf = (unsigned short*)(ws);               // 65536*2304*2 = 301,989,888
    unsigned short* wqkvT  = (unsigned short*)(ws + 301989888);   // 2304*768*2   =   3,538,944
    float*          part   = (float*)(ws + 305528832);            // 1536*4096*4  =  25,165,824
    unsigned short* MT     = (unsigned short*)(ws + 330694656);   // 16*768*768*2 =  18,874,368
    // scratch in d_out (dead before GEMM2 writes out):
    unsigned short* xb   = (unsigned short*)d_out;                          // 100.7 MB
    unsigned short* gkvb = (unsigned short*)((char*)d_out + 134217728);     // 1.57 MB
    unsigned short* wpT  = (unsigned short*)((char*)d_out + 136314880);     // 1.18 MB

    // 1) convert x -> bf16
    k_cvt_bf16<<<2048, 256, 0, stream>>>(x, xb, 50331648L);
    // 2) transpose+convert weights
    k_wqkvT<<<864, 256, 0, stream>>>(w_qkv, wqkvT);
    k_wprojT<<<288, 256, 0, stream>>>(w_proj, wpT);
    // 3) GEMM1: qkv_bf[65536][2304] = xb @ wqkvT^T, gelu on q columns (<768)
    k_gemm256<true, false, true, false><<<2304, 512, 0, stream>>>(
        xb, 768, wqkvT, 768, qkv_bf, 2304, nullptr, 9, 768);
    // 4) kv partials over 8 n-chunks
    k_kvpart<<<1536, 256, 0, stream>>>(qkv_bf, part);
    // 5a) reduce + scale + gelu -> gkvb
    k_gkv<<<192, 256, 0, stream>>>(part, gkvb);
    // 5b) M = gkv @ wproj-rows -> MT[b][c][hd]
    k_M<<<576, 256, 0, stream>>>(gkvb, wpT, MT);
    // 6) GEMM2: out[65536][768] = gelu(q) @ MT_b^T + b_proj
    k_gemm256<false, true, false, true><<<768, 512, 0, stream>>>(
        qkv_bf, 2304, MT, 768, out, 768, b_proj, 3, 768);
}

// Round 4
// 514.806 us; speedup vs baseline: 2.0260x; 1.0020x over previous
//
#include <hip/hip_runtime.h>
#include <hip/hip_bf16.h>

// Problem: B=16, N=4096, C=768, H=12, D=64
// x[16,4096,768] f32; w_qkv[768,2304] f32; w_proj[768,768] f32; b_proj[768] f32
// out[16,4096,768] f32

typedef __attribute__((ext_vector_type(8))) short short8_t;
typedef __attribute__((ext_vector_type(4))) float f32x4_t;

typedef __attribute__((address_space(1))) void as1_void;
typedef __attribute__((address_space(3))) void as3_void;

__device__ __forceinline__ void gload_lds16(const void* g, void* l) {
    __builtin_amdgcn_global_load_lds(
        (as1_void*)(unsigned long long)(g),
        (as3_void*)(unsigned long long)(l), 16, 0, 0);
}

__device__ __forceinline__ float gelu_exact(float x) {
    return 0.5f * x * (1.0f + erff(x * 0.7071067811865475f));
}

__device__ __forceinline__ unsigned short to_bf16(float f) {
    __hip_bfloat16 h = __float2bfloat16(f);
    return *reinterpret_cast<unsigned short*>(&h);
}

// ---------------- f32 -> bf16 convert (vectorized) ----------------
__global__ __launch_bounds__(256) void k_cvt_bf16(const float* __restrict__ in,
                                                  unsigned short* __restrict__ out,
                                                  long n) {
    long i = (long)blockIdx.x * blockDim.x + threadIdx.x;
    long stride = (long)gridDim.x * blockDim.x;
    for (long idx = i * 4; idx < n; idx += stride * 4) {
        float4 v = *(const float4*)(in + idx);
        ushort4 o;
        o.x = to_bf16(v.x); o.y = to_bf16(v.y); o.z = to_bf16(v.z); o.w = to_bf16(v.w);
        *(ushort4*)(out + idx) = o;
    }
}

// ---------------- transpose+convert w_qkv [768][2304] -> [2304][768] bf16 ----------------
__global__ __launch_bounds__(256) void k_wqkvT(const float* __restrict__ w,
                                               unsigned short* __restrict__ wT) {
    int gid = blockIdx.x * 256 + threadIdx.x;       // 2304 * 96
    int c = gid / 96, rblk = gid % 96;
    int r0 = rblk * 8;
    short8_t o;
#pragma unroll
    for (int i = 0; i < 8; ++i)
        o[i] = (short)to_bf16(w[(size_t)(r0 + i) * 2304 + c]);
    *(short8_t*)(wT + (size_t)c * 768 + r0) = o;
}

// ---------------- transpose+convert w_proj [768][768] -> wpT[c][r] bf16 ----------------
__global__ __launch_bounds__(256) void k_wprojT(const float* __restrict__ w,
                                                unsigned short* __restrict__ wT) {
    int gid = blockIdx.x * 256 + threadIdx.x;       // 768 * 96
    int c = gid / 96, rblk = gid % 96;
    int r0 = rblk * 8;
    short8_t o;
#pragma unroll
    for (int i = 0; i < 8; ++i)
        o[i] = (short)to_bf16(w[(size_t)(r0 + i) * 768 + c]);
    *(short8_t*)(wT + (size_t)c * 768 + r0) = o;
}

// ================= 256x256 8-phase GEMM: C = A @ Bt^T =================
// Phases split by (ks, mi-half): reads spread 8/4/8/4 per phase (m201 pattern).
template<bool GELU_EPI, bool BATCHED_B, bool BF16_OUT, bool BIAS>
__global__ __launch_bounds__(512, 2)
void k_gemm256(const unsigned short* __restrict__ A, int lda,
               const unsigned short* __restrict__ Bt, int ldb,
               void* __restrict__ Cout, int ldc,
               const float* __restrict__ bias,
               int tiles_n, int K) {
    __shared__ __attribute__((aligned(16))) unsigned short lds[2][2][2][128 * 64];

    const int nwg = gridDim.x;
    int bid = blockIdx.x;
    bid = (bid & 7) * (nwg >> 3) + (bid >> 3);

    const int tn = bid % tiles_n, tm = bid / tiles_n;
    const int row0 = tm * 256, col0 = tn * 256;

    const unsigned short* Bb = Bt;
    if (BATCHED_B) Bb += (size_t)(row0 >> 12) * 768 * 768;

    const int tid = threadIdx.x;
    const int lane = tid & 63;
    const int w = tid >> 6;
    const int wm = w >> 2;
    const int wn = w & 3;
    const int lr = lane & 15, lg = lane >> 4;

    const int c0 = tid, c1 = 512 + tid;
    const int sr0 = c0 >> 3, sk0 = (c0 & 7) ^ (sr0 & 7);
    const int sr1 = c1 >> 3, sk1 = (c1 & 7) ^ (sr1 & 7);

    auto stageA = [&](int buf, int half, int kt) {
        const unsigned short* base = A + (size_t)(row0 + half * 128) * lda + kt * 64;
        gload_lds16(base + (size_t)sr0 * lda + sk0 * 8, &lds[0][buf][half][c0 * 8]);
        gload_lds16(base + (size_t)sr1 * lda + sk1 * 8, &lds[0][buf][half][c1 * 8]);
    };
    auto stageB = [&](int buf, int half, int kt) {
        const unsigned short* base = Bb + (size_t)(col0 + half * 128) * ldb + kt * 64;
        gload_lds16(base + (size_t)sr0 * ldb + sk0 * 8, &lds[1][buf][half][c0 * 8]);
        gload_lds16(base + (size_t)sr1 * ldb + sk1 * 8, &lds[1][buf][half][c1 * 8]);
    };
    auto ldA = [&](int buf, int mi, int ks) -> short8_t {
        int row = mi * 16 + lr;
        int kc = (ks * 4 + lg) ^ (row & 7);
        return *(const short8_t*)&lds[0][buf][wm][row * 64 + kc * 8];
    };
    auto ldB = [&](int buf, int nj, int ks) -> short8_t {
        int row = wn * 64 + nj * 16 + lr;
        int half = row >> 7, rl = row & 127;
        int kc = (ks * 4 + lg) ^ (rl & 7);
        return *(const short8_t*)&lds[1][buf][half][rl * 64 + kc * 8];
    };

    f32x4_t acc[8][4] = {};
    short8_t bfrag[4];

#define FENCE asm volatile("" ::: "memory")
#define PHASE(q, buf, STAGE_STMT, VM_STMT)                                      \
    {                                                                           \
        short8_t afr[4];                                                        \
        if (((q) & 1) == 0) {                                                   \
            _Pragma("unroll") for (int nj = 0; nj < 4; ++nj)                    \
                bfrag[nj] = ldB(buf, nj, (q) >> 1);                             \
        }                                                                       \
        _Pragma("unroll") for (int mi = 0; mi < 4; ++mi)                        \
            afr[mi] = ldA(buf, ((q) & 1) * 4 + mi, (q) >> 1);                   \
        STAGE_STMT;                                                             \
        VM_STMT;                                                                \
        FENCE;                                                                  \
        __builtin_amdgcn_s_barrier();                                           \
        FENCE;                                                                  \
        __builtin_amdgcn_s_setprio(1);                                          \
        _Pragma("unroll") for (int mi = 0; mi < 4; ++mi)                        \
            _Pragma("unroll") for (int nj = 0; nj < 4; ++nj)                    \
                acc[((q) & 1) * 4 + mi][nj] = __builtin_amdgcn_mfma_f32_16x16x32_bf16( \
                    afr[mi], bfrag[nj], acc[((q) & 1) * 4 + mi][nj], 0, 0, 0);  \
        __builtin_amdgcn_s_setprio(0);                                          \
        FENCE;                                                                  \
        __builtin_amdgcn_s_barrier();                                           \
        FENCE;                                                                  \
    }

    const int nt = K >> 6;
    const int niter = nt >> 1;

    stageA(0, 0, 0); stageA(0, 1, 0); stageB(0, 0, 0); stageB(0, 1, 0);
    stageB(1, 0, 1); stageB(1, 1, 1);
    asm volatile("s_waitcnt vmcnt(4)" ::: "memory");
    __builtin_amdgcn_s_barrier();
    FENCE;

    for (int it = 0; it < niter; ++it) {
        const int t1 = 2 * it + 1;
        const int tA = (2 * it + 2 < nt) ? 2 * it + 2 : 0;
        const int tB = (2 * it + 3 < nt) ? 2 * it + 3 : 0;
        PHASE(0, 0, stageA(1, 0, t1), (void)0);
        PHASE(1, 0, stageA(1, 1, t1), (void)0);
        PHASE(2, 0, stageB(0, 0, tA), (void)0);
        PHASE(3, 0, stageB(0, 1, tA), asm volatile("s_waitcnt vmcnt(4)" ::: "memory"));
        PHASE(0, 1, stageA(0, 0, tA), (void)0);
        PHASE(1, 1, stageA(0, 1, tA), (void)0);
        PHASE(2, 1, stageB(1, 0, tB), (void)0);
        PHASE(3, 1, stageB(1, 1, tB), asm volatile("s_waitcnt vmcnt(4)" ::: "memory"));
    }
    asm volatile("s_waitcnt vmcnt(0)" ::: "memory");
#undef PHASE
#undef FENCE

    const int rbase = row0 + wm * 128 + (lg << 2);
    const int cbase = col0 + wn * 64 + lr;
#pragma unroll
    for (int mi = 0; mi < 8; ++mi)
#pragma unroll
        for (int nj = 0; nj < 4; ++nj)
#pragma unroll
            for (int r = 0; r < 4; ++r) {
                int row = rbase + mi * 16 + r;
                int col = cbase + nj * 16;
                float v = acc[mi][nj][r];
                if (GELU_EPI) { if (col < 768) v = gelu_exact(v); }
                if (BIAS) v += bias[col];
                if (BF16_OUT)
                    ((unsigned short*)Cout)[(size_t)row * ldc + col] = to_bf16(v);
                else
                    ((float*)Cout)[(size_t)row * ldc + col] = v;
            }
}

// ---------------- kv partials: part[ch*192+bh][d][e] = sum_{n in chunk} k[n,d]*v[n,e] ----------------
__global__ __launch_bounds__(256) void k_kvpart(const unsigned short* __restrict__ qkv,
                                                float* __restrict__ part) {
    const int bid = blockIdx.x;
    const int ch = bid / 192, bh = bid % 192;
    const int b = bh / 12, h = bh % 12;
    const size_t rowbase = (size_t)b * 4096 + (size_t)ch * 512;
    const unsigned short* kptr = qkv + 768 + h * 64;
    const unsigned short* vptr = qkv + 1536 + h * 64;

    __shared__ __attribute__((aligned(16))) unsigned short kT[64 * 64];
    __shared__ __attribute__((aligned(16))) unsigned short vT[64 * 64];

    const int tid = threadIdx.x, lane = tid & 63, w = tid >> 6;
    const int np = tid >> 3;
    const int g = tid & 7;

    f32x4_t acc[4] = {};

    for (int it = 0; it < 8; ++it) {
        const size_t r0 = (rowbase + it * 64 + 2 * np) * 2304;
        short8_t k0 = *(const short8_t*)(kptr + r0 + g * 8);
        short8_t k1 = *(const short8_t*)(kptr + r0 + 2304 + g * 8);
        short8_t v0 = *(const short8_t*)(vptr + r0 + g * 8);
        short8_t v1 = *(const short8_t*)(vptr + r0 + 2304 + g * 8);
        __syncthreads();
#pragma unroll
        for (int j = 0; j < 8; ++j) {
            const int d = g * 8 + j;
            const int e = d * 64 + ((2 * np) ^ (((d ^ (d >> 3)) & 7) << 3));
            *(unsigned int*)(kT + e) =
                (unsigned int)(unsigned short)k0[j] | ((unsigned int)(unsigned short)k1[j] << 16);
            *(unsigned int*)(vT + e) =
                (unsigned int)(unsigned short)v0[j] | ((unsigned int)(unsigned short)v1[j] << 16);
        }
        __syncthreads();
        const int lr = lane & 15, lg = lane >> 4;
#pragma unroll
        for (int ks = 0; ks < 2; ++ks) {
            const int d = w * 16 + lr;
            short8_t a = *(const short8_t*)(kT + d * 64 +
                (((ks * 4 + lg) ^ ((d ^ (d >> 3)) & 7)) << 3));
#pragma unroll
            for (int nj = 0; nj < 4; ++nj) {
                const int e2 = nj * 16 + lr;
                short8_t bf = *(const short8_t*)(vT + e2 * 64 +
                    (((ks * 4 + lg) ^ ((e2 ^ (e2 >> 3)) & 7)) << 3));
                acc[nj] = __builtin_amdgcn_mfma_f32_16x16x32_bf16(a, bf, acc[nj], 0, 0, 0);
            }
        }
    }

    float* pout = part + (size_t)bid * 4096;
    const int rb = w * 16 + ((lane >> 4) << 2);
    const int cb = lane & 15;
#pragma unroll
    for (int nj = 0; nj < 4; ++nj)
#pragma unroll
        for (int r = 0; r < 4; ++r)
            pout[(rb + r) * 64 + nj * 16 + cb] = acc[nj][r];
}

// ---------------- reduce partials + scale + gelu -> gkvb bf16 [bh][64][64] ----------------
__global__ __launch_bounds__(256) void k_gkv(const float* __restrict__ part,
                                             unsigned short* __restrict__ gkvb) {
    const int bh = blockIdx.x;           // 0..191
    const int tid = threadIdx.x;
    const float* p0 = part + (size_t)bh * 4096 + tid * 16;
    float f[16];
#pragma unroll
    for (int j = 0; j < 16; ++j) f[j] = 0.f;
#pragma unroll
    for (int ch = 0; ch < 8; ++ch) {
        const float* p = p0 + (size_t)ch * 192 * 4096;
#pragma unroll
        for (int j4 = 0; j4 < 4; ++j4) {
            float4 v = *(const float4*)(p + j4 * 4);
            f[j4 * 4 + 0] += v.x; f[j4 * 4 + 1] += v.y;
            f[j4 * 4 + 2] += v.z; f[j4 * 4 + 3] += v.w;
        }
    }
    short8_t o0, o1;
#pragma unroll
    for (int j = 0; j < 8; ++j) {
        o0[j] = (short)to_bf16(gelu_exact(f[j] * 0.125f));
        o1[j] = (short)to_bf16(gelu_exact(f[8 + j] * 0.125f));
    }
    unsigned short* dst = gkvb + (size_t)bh * 4096 + tid * 16;
    *(short8_t*)(dst) = o0;
    *(short8_t*)(dst + 8) = o1;
}

// ---------------- M[d][c] = sum_e gkv[d][e]*wproj[h*64+e][c], stored as MT[b][c][hd] bf16 ----------------
__global__ __launch_bounds__(256) void k_M(const unsigned short* __restrict__ gkvb,
                                           const unsigned short* __restrict__ wpT,
                                           unsigned short* __restrict__ MT) {
    __shared__ __attribute__((aligned(16))) unsigned short As[64 * 64];
    __shared__ __attribute__((aligned(16))) unsigned short Bs[256 * 64];

    const int bid = blockIdx.x;
    const int bh = bid / 3, ct = bid % 3;
    const int b = bh / 12, h = bh % 12;
    const int c0 = ct * 256;
    const int tid = threadIdx.x, lane = tid & 63, w = tid >> 6;
    const int lr = lane & 15, lg = lane >> 4;

    short8_t ra[2], rb[8];
#pragma unroll
    for (int i = 0; i < 2; ++i) {
        int ch = i * 256 + tid, row = ch >> 3, kc = ch & 7;
        ra[i] = *(const short8_t*)(gkvb + (size_t)bh * 4096 + row * 64 + kc * 8);
    }
#pragma unroll
    for (int i = 0; i < 8; ++i) {
        int ch = i * 256 + tid, row = ch >> 3, kc = ch & 7;
        rb[i] = *(const short8_t*)(wpT + (size_t)(c0 + row) * 768 + h * 64 + kc * 8);
    }
#pragma unroll
    for (int i = 0; i < 2; ++i) {
        int ch = i * 256 + tid, row = ch >> 3, kc = ch & 7;
        *(short8_t*)(As + row * 64 + ((kc ^ (row & 7)) * 8)) = ra[i];
    }
#pragma unroll
    for (int i = 0; i < 8; ++i) {
        int ch = i * 256 + tid, row = ch >> 3, kc = ch & 7;
        *(short8_t*)(Bs + row * 64 + ((kc ^ (row & 7)) * 8)) = rb[i];
    }
    __syncthreads();

    f32x4_t acc[4][4] = {};
#pragma unroll
    for (int ks = 0; ks < 2; ++ks) {
        short8_t a[4], bfr[4];
#pragma unroll
        for (int mi = 0; mi < 4; ++mi) {
            int row = mi * 16 + lr;
            a[mi] = *(const short8_t*)(As + row * 64 + (((ks * 4 + lg) ^ (row & 7)) * 8));
        }
#pragma unroll
        for (int nj = 0; nj < 4; ++nj) {
            int row = w * 64 + nj * 16 + lr;
            bfr[nj] = *(const short8_t*)(Bs + row * 64 + (((ks * 4 + lg) ^ (row & 7)) * 8));
        }
#pragma unroll
        for (int mi = 0; mi < 4; ++mi)
#pragma unroll
            for (int nj = 0; nj < 4; ++nj)
                acc[mi][nj] = __builtin_amdgcn_mfma_f32_16x16x32_bf16(a[mi], bfr[nj], acc[mi][nj], 0, 0, 0);
    }
    __syncthreads();

#pragma unroll
    for (int mi = 0; mi < 4; ++mi)
#pragma unroll
        for (int nj = 0; nj < 4; ++nj) {
            unsigned int w0 = (unsigned int)to_bf16(acc[mi][nj][0]) |
                              ((unsigned int)to_bf16(acc[mi][nj][1]) << 16);
            unsigned int w1 = (unsigned int)to_bf16(acc[mi][nj][2]) |
                              ((unsigned int)to_bf16(acc[mi][nj][3]) << 16);
            uint2 pk; pk.x = w0; pk.y = w1;
            *(uint2*)(Bs + (w * 64 + nj * 16 + lr) * 64 + mi * 16 + lg * 4) = pk;
        }
    __syncthreads();
#pragma unroll
    for (int i = 0; i < 8; ++i) {
        int ch = i * 256 + tid, cl = ch >> 3, dk = ch & 7;
        short8_t v = *(const short8_t*)(Bs + cl * 64 + dk * 8);
        *(short8_t*)(MT + ((size_t)(b * 768) + c0 + cl) * 768 + h * 64 + dk * 8) = v;
    }
}

extern "C" void kernel_launch(void* const* d_in, const int* in_sizes, int n_in,
                              void* d_out, int out_size, void* d_ws, size_t ws_size,
                              hipStream_t stream) {
    const float* x      = (const float*)d_in[0];
    const float* w_qkv  = (const float*)d_in[1];
    const float* w_proj = (const float*)d_in[2];
    const float* b_proj = (const float*)d_in[3];
    float* out = (float*)d_out;
    char* ws = (char*)d_ws;

    unsigned short* qkv_bf = (unsigned short*)(ws);               // 65536*2304*2 = 301,989,888
    unsigned short* wqkvT  = (unsigned short*)(ws + 301989888);   // 2304*768*2   =   3,538,944
    float*          part   = (float*)(ws + 305528832);            // 1536*4096*4  =  25,165,824
    unsigned short* MT     = (unsigned short*)(ws + 330694656);   // 16*768*768*2 =  18,874,368
    unsigned short* xb   = (unsigned short*)d_out;                          // 100.7 MB
    unsigned short* gkvb = (unsigned short*)((char*)d_out + 134217728);     // 1.57 MB
    unsigned short* wpT  = (unsigned short*)((char*)d_out + 136314880);     // 1.18 MB

    k_cvt_bf16<<<2048, 256, 0, stream>>>(x, xb, 50331648L);
    k_wqkvT<<<864, 256, 0, stream>>>(w_qkv, wqkvT);
    k_wprojT<<<288, 256, 0, stream>>>(w_proj, wpT);
    k_gemm256<true, false, true, false><<<2304, 512, 0, stream>>>(
        xb, 768, wqkvT, 768, qkv_bf, 2304, nullptr, 9, 768);
    k_kvpart<<<1536, 256, 0, stream>>>(qkv_bf, part);
    k_gkv<<<192, 256, 0, stream>>>(part, gkvb);
    k_M<<<576, 256, 0, stream>>>(gkvb, wpT, MT);
    k_gemm256<false, true, false, true><<<768, 512, 0, stream>>>(
        qkv_bf, 2304, MT, 768, out, 768, b_proj, 3, 768);
}

// Round 5
// 506.064 us; speedup vs baseline: 2.0610x; 1.0173x over previous
//
#include <hip/hip_runtime.h>
#include <hip/hip_bf16.h>

// Problem: B=16, N=4096, C=768, H=12, D=64
// x[16,4096,768] f32; w_qkv[768,2304] f32; w_proj[768,768] f32; b_proj[768] f32
// out[16,4096,768] f32

typedef __attribute__((ext_vector_type(8))) short short8_t;
typedef __attribute__((ext_vector_type(4))) float f32x4_t;

typedef __attribute__((address_space(1))) void as1_void;
typedef __attribute__((address_space(3))) void as3_void;

__device__ __forceinline__ void gload_lds16(const void* g, void* l) {
    __builtin_amdgcn_global_load_lds(
        (as1_void*)(unsigned long long)(g),
        (as3_void*)(unsigned long long)(l), 16, 0, 0);
}

__device__ __forceinline__ float gelu_exact(float x) {
    return 0.5f * x * (1.0f + erff(x * 0.7071067811865475f));
}

__device__ __forceinline__ unsigned short to_bf16(float f) {
    __hip_bfloat16 h = __float2bfloat16(f);
    return *reinterpret_cast<unsigned short*>(&h);
}

__device__ __forceinline__ f32x4_t mfma16(short8_t a, short8_t b, f32x4_t c) {
    return __builtin_amdgcn_mfma_f32_16x16x32_bf16(a, b, c, 0, 0, 0);
}

// ---------------- f32 -> bf16 convert (vectorized) ----------------
__global__ __launch_bounds__(256) void k_cvt_bf16(const float* __restrict__ in,
                                                  unsigned short* __restrict__ out,
                                                  long n) {
    long i = (long)blockIdx.x * blockDim.x + threadIdx.x;
    long stride = (long)gridDim.x * blockDim.x;
    for (long idx = i * 4; idx < n; idx += stride * 4) {
        float4 v = *(const float4*)(in + idx);
        ushort4 o;
        o.x = to_bf16(v.x); o.y = to_bf16(v.y); o.z = to_bf16(v.z); o.w = to_bf16(v.w);
        *(ushort4*)(out + idx) = o;
    }
}

// ---------------- transpose+convert w_qkv [768][2304] -> [2304][768] bf16 ----------------
__global__ __launch_bounds__(256) void k_wqkvT(const float* __restrict__ w,
                                               unsigned short* __restrict__ wT) {
    int gid = blockIdx.x * 256 + threadIdx.x;       // 2304 * 96
    int c = gid / 96, rblk = gid % 96;
    int r0 = rblk * 8;
    short8_t o;
#pragma unroll
    for (int i = 0; i < 8; ++i)
        o[i] = (short)to_bf16(w[(size_t)(r0 + i) * 2304 + c]);
    *(short8_t*)(wT + (size_t)c * 768 + r0) = o;
}

// ---------------- transpose+convert w_proj [768][768] -> wpT[c][r] bf16 ----------------
__global__ __launch_bounds__(256) void k_wprojT(const float* __restrict__ w,
                                                unsigned short* __restrict__ wT) {
    int gid = blockIdx.x * 256 + threadIdx.x;       // 768 * 96
    int c = gid / 96, rblk = gid % 96;
    int r0 = rblk * 8;
    short8_t o;
#pragma unroll
    for (int i = 0; i < 8; ++i)
        o[i] = (short)to_bf16(w[(size_t)(r0 + i) * 768 + c]);
    *(short8_t*)(wT + (size_t)c * 768 + r0) = o;
}

// ================= 256x256 8-phase GEMM: C = A @ Bt^T  (m201-faithful) =================
// Staging: 1 half-tile per phase into the just-freed slot (B-slots die at q0,
// A-slots at q3); vmcnt(6) only at phases 4/8; explicit lgkmcnt(0)+sched_barrier
// before each 16-MFMA cluster; lgkmcnt(8) pacing on 12-read phases.
template<bool GELU_EPI, bool BATCHED_B, bool BF16_OUT, bool BIAS>
__global__ __launch_bounds__(512, 2)
void k_gemm256(const unsigned short* __restrict__ A, int lda,
               const unsigned short* __restrict__ Bt, int ldb,
               void* __restrict__ Cout, int ldc,
               const float* __restrict__ bias,
               int tiles_n, int K) {
    __shared__ __attribute__((aligned(16))) unsigned short lds[2][2][2][128 * 64];

    const int nwg = gridDim.x;
    int bid = blockIdx.x;
    bid = (bid & 7) * (nwg >> 3) + (bid >> 3);

    const int tn = bid % tiles_n, tm = bid / tiles_n;
    const int row0 = tm * 256, col0 = tn * 256;

    const unsigned short* Bb = Bt;
    if (BATCHED_B) Bb += (size_t)(row0 >> 12) * 768 * 768;

    const int tid = threadIdx.x;
    const int lane = tid & 63;
    const int w = tid >> 6;
    const int wm = w >> 2;
    const int wn = w & 3;
    const int lr = lane & 15, lg = lane >> 4;

    const int c0 = tid, c1 = 512 + tid;
    const int sr0 = c0 >> 3, sk0 = (c0 & 7) ^ (sr0 & 7);
    const int sr1 = c1 >> 3, sk1 = (c1 & 7) ^ (sr1 & 7);

    auto stageA = [&](int buf, int half, int kt) {
        const unsigned short* base = A + (size_t)(row0 + half * 128) * lda + kt * 64;
        gload_lds16(base + (size_t)sr0 * lda + sk0 * 8, &lds[0][buf][half][c0 * 8]);
        gload_lds16(base + (size_t)sr1 * lda + sk1 * 8, &lds[0][buf][half][c1 * 8]);
    };
    auto stageB = [&](int buf, int half, int kt) {
        const unsigned short* base = Bb + (size_t)(col0 + half * 128) * ldb + kt * 64;
        gload_lds16(base + (size_t)sr0 * ldb + sk0 * 8, &lds[1][buf][half][c0 * 8]);
        gload_lds16(base + (size_t)sr1 * ldb + sk1 * 8, &lds[1][buf][half][c1 * 8]);
    };
    auto ldA = [&](int buf, int mi, int ks) -> short8_t {
        int row = mi * 16 + lr;
        int kc = (ks * 4 + lg) ^ (row & 7);
        return *(const short8_t*)&lds[0][buf][wm][row * 64 + kc * 8];
    };
    auto ldB = [&](int buf, int nj, int ks) -> short8_t {
        int row = wn * 64 + nj * 16 + lr;
        int half = row >> 7, rl = row & 127;
        int kc = (ks * 4 + lg) ^ (rl & 7);
        return *(const short8_t*)&lds[1][buf][half][rl * 64 + kc * 8];
    };

    f32x4_t acc[8][4] = {};
    short8_t bfrag[4][2];

#define FENCE asm volatile("" ::: "memory")
// one phase: mi-pair (2q, 2q+1) x full K=64 -> 16 MFMAs; q==0 also reads all 8 B-frags.
#define PH(q, buf, STAGE_STMT, EXTRA_WAIT)                                      \
    {                                                                           \
        if ((q) == 0) {                                                         \
            _Pragma("unroll") for (int nj = 0; nj < 4; ++nj)                    \
                _Pragma("unroll") for (int ks = 0; ks < 2; ++ks)                \
                    bfrag[nj][ks] = ldB(buf, nj, ks);                           \
        }                                                                       \
        short8_t afr0 = ldA(buf, 2 * (q), 0);                                   \
        short8_t afr1 = ldA(buf, 2 * (q), 1);                                   \
        short8_t afr2 = ldA(buf, 2 * (q) + 1, 0);                               \
        short8_t afr3 = ldA(buf, 2 * (q) + 1, 1);                               \
        STAGE_STMT;                                                             \
        EXTRA_WAIT;                                                             \
        FENCE;                                                                  \
        __builtin_amdgcn_s_barrier();                                           \
        asm volatile("s_waitcnt lgkmcnt(0)" ::: "memory");                      \
        __builtin_amdgcn_sched_barrier(0);                                      \
        __builtin_amdgcn_s_setprio(1);                                          \
        _Pragma("unroll") for (int nj = 0; nj < 4; ++nj) {                      \
            acc[2 * (q)][nj]     = mfma16(afr0, bfrag[nj][0], acc[2 * (q)][nj]);     \
            acc[2 * (q)][nj]     = mfma16(afr1, bfrag[nj][1], acc[2 * (q)][nj]);     \
            acc[2 * (q) + 1][nj] = mfma16(afr2, bfrag[nj][0], acc[2 * (q) + 1][nj]); \
            acc[2 * (q) + 1][nj] = mfma16(afr3, bfrag[nj][1], acc[2 * (q) + 1][nj]); \
        }                                                                       \
        __builtin_amdgcn_s_setprio(0);                                          \
        FENCE;                                                                  \
        __builtin_amdgcn_s_barrier();                                           \
        FENCE;                                                                  \
    }

    const int nt = K >> 6;          // 12 for K=768
    const int niter = nt >> 1;

    // prologue: tile0 full, then tile1's B0,B1,A0 (A1 staged at loop q0)
    stageA(0, 0, 0); stageA(0, 1, 0); stageB(0, 0, 0); stageB(0, 1, 0);
    asm volatile("s_waitcnt vmcnt(4)" ::: "memory");
    stageB(1, 0, 1); stageB(1, 1, 1); stageA(1, 0, 1);
    asm volatile("s_waitcnt vmcnt(6)" ::: "memory");
    __builtin_amdgcn_s_barrier();
    FENCE;

    for (int it = 0; it < niter; ++it) {
        const int t1 = 2 * it + 1;
        const int tA = (2 * it + 2 < nt) ? 2 * it + 2 : 0;
        const int tB = (2 * it + 3 < nt) ? 2 * it + 3 : 0;
        // q0-q3: compute tile 2it from buf0
        PH(0, 0, stageA(1, 1, t1), asm volatile("s_waitcnt lgkmcnt(8)" ::: "memory"));
        PH(1, 0, stageB(0, 0, tA), (void)0);
        PH(2, 0, stageB(0, 1, tA), (void)0);
        PH(3, 0, stageA(0, 0, tA), asm volatile("s_waitcnt vmcnt(6)" ::: "memory"));
        // q4-q7: compute tile 2it+1 from buf1
        PH(0, 1, stageA(0, 1, tA), asm volatile("s_waitcnt lgkmcnt(8)" ::: "memory"));
        PH(1, 1, stageB(1, 0, tB), (void)0);
        PH(2, 1, stageB(1, 1, tB), (void)0);
        PH(3, 1, stageA(1, 0, tB), asm volatile("s_waitcnt vmcnt(6)" ::: "memory"));
    }
    asm volatile("s_waitcnt vmcnt(0)" ::: "memory");
#undef PH
#undef FENCE

    const int rbase = row0 + wm * 128 + (lg << 2);
    const int cbase = col0 + wn * 64 + lr;
#pragma unroll
    for (int mi = 0; mi < 8; ++mi)
#pragma unroll
        for (int nj = 0; nj < 4; ++nj)
#pragma unroll
            for (int r = 0; r < 4; ++r) {
                int row = rbase + mi * 16 + r;
                int col = cbase + nj * 16;
                float v = acc[mi][nj][r];
                if (GELU_EPI) { if (col < 768) v = gelu_exact(v); }
                if (BIAS) v += bias[col];
                if (BF16_OUT)
                    ((unsigned short*)Cout)[(size_t)row * ldc + col] = to_bf16(v);
                else
                    ((float*)Cout)[(size_t)row * ldc + col] = v;
            }
}

// ---------------- kv partials: part[ch*192+bh][d][e] = sum_{n in chunk} k[n,d]*v[n,e] ----------------
__global__ __launch_bounds__(256) void k_kvpart(const unsigned short* __restrict__ qkv,
                                                float* __restrict__ part) {
    const int bid = blockIdx.x;
    const int ch = bid / 192, bh = bid % 192;
    const int b = bh / 12, h = bh % 12;
    const size_t rowbase = (size_t)b * 4096 + (size_t)ch * 512;
    const unsigned short* kptr = qkv + 768 + h * 64;
    const unsigned short* vptr = qkv + 1536 + h * 64;

    __shared__ __attribute__((aligned(16))) unsigned short kT[64 * 64];
    __shared__ __attribute__((aligned(16))) unsigned short vT[64 * 64];

    const int tid = threadIdx.x, lane = tid & 63, w = tid >> 6;
    const int np = tid >> 3;
    const int g = tid & 7;

    f32x4_t acc[4] = {};

    for (int it = 0; it < 8; ++it) {
        const size_t r0 = (rowbase + it * 64 + 2 * np) * 2304;
        short8_t k0 = *(const short8_t*)(kptr + r0 + g * 8);
        short8_t k1 = *(const short8_t*)(kptr + r0 + 2304 + g * 8);
        short8_t v0 = *(const short8_t*)(vptr + r0 + g * 8);
        short8_t v1 = *(const short8_t*)(vptr + r0 + 2304 + g * 8);
        __syncthreads();
#pragma unroll
        for (int j = 0; j < 8; ++j) {
            const int d = g * 8 + j;
            const int e = d * 64 + ((2 * np) ^ (((d ^ (d >> 3)) & 7) << 3));
            *(unsigned int*)(kT + e) =
                (unsigned int)(unsigned short)k0[j] | ((unsigned int)(unsigned short)k1[j] << 16);
            *(unsigned int*)(vT + e) =
                (unsigned int)(unsigned short)v0[j] | ((unsigned int)(unsigned short)v1[j] << 16);
        }
        __syncthreads();
        const int lr = lane & 15, lg = lane >> 4;
#pragma unroll
        for (int ks = 0; ks < 2; ++ks) {
            const int d = w * 16 + lr;
            short8_t a = *(const short8_t*)(kT + d * 64 +
                (((ks * 4 + lg) ^ ((d ^ (d >> 3)) & 7)) << 3));
#pragma unroll
            for (int nj = 0; nj < 4; ++nj) {
                const int e2 = nj * 16 + lr;
                short8_t bf = *(const short8_t*)(vT + e2 * 64 +
                    (((ks * 4 + lg) ^ ((e2 ^ (e2 >> 3)) & 7)) << 3));
                acc[nj] = __builtin_amdgcn_mfma_f32_16x16x32_bf16(a, bf, acc[nj], 0, 0, 0);
            }
        }
    }

    float* pout = part + (size_t)bid * 4096;
    const int rb = w * 16 + ((lane >> 4) << 2);
    const int cb = lane & 15;
#pragma unroll
    for (int nj = 0; nj < 4; ++nj)
#pragma unroll
        for (int r = 0; r < 4; ++r)
            pout[(rb + r) * 64 + nj * 16 + cb] = acc[nj][r];
}

// ---------------- reduce partials + scale + gelu -> gkvb bf16 [bh][64][64] ----------------
__global__ __launch_bounds__(256) void k_gkv(const float* __restrict__ part,
                                             unsigned short* __restrict__ gkvb) {
    const int bh = blockIdx.x;           // 0..191
    const int tid = threadIdx.x;
    const float* p0 = part + (size_t)bh * 4096 + tid * 16;
    float f[16];
#pragma unroll
    for (int j = 0; j < 16; ++j) f[j] = 0.f;
#pragma unroll
    for (int ch = 0; ch < 8; ++ch) {
        const float* p = p0 + (size_t)ch * 192 * 4096;
#pragma unroll
        for (int j4 = 0; j4 < 4; ++j4) {
            float4 v = *(const float4*)(p + j4 * 4);
            f[j4 * 4 + 0] += v.x; f[j4 * 4 + 1] += v.y;
            f[j4 * 4 + 2] += v.z; f[j4 * 4 + 3] += v.w;
        }
    }
    short8_t o0, o1;
#pragma unroll
    for (int j = 0; j < 8; ++j) {
        o0[j] = (short)to_bf16(gelu_exact(f[j] * 0.125f));
        o1[j] = (short)to_bf16(gelu_exact(f[8 + j] * 0.125f));
    }
    unsigned short* dst = gkvb + (size_t)bh * 4096 + tid * 16;
    *(short8_t*)(dst) = o0;
    *(short8_t*)(dst + 8) = o1;
}

// ---------------- M[d][c] = sum_e gkv[d][e]*wproj[h*64+e][c], stored as MT[b][c][hd] bf16 ----------------
__global__ __launch_bounds__(256) void k_M(const unsigned short* __restrict__ gkvb,
                                           const unsigned short* __restrict__ wpT,
                                           unsigned short* __restrict__ MT) {
    __shared__ __attribute__((aligned(16))) unsigned short As[64 * 64];
    __shared__ __attribute__((aligned(16))) unsigned short Bs[256 * 64];

    const int bid = blockIdx.x;
    const int bh = bid / 3, ct = bid % 3;
    const int b = bh / 12, h = bh % 12;
    const int c0 = ct * 256;
    const int tid = threadIdx.x, lane = tid & 63, w = tid >> 6;
    const int lr = lane & 15, lg = lane >> 4;

    short8_t ra[2], rb[8];
#pragma unroll
    for (int i = 0; i < 2; ++i) {
        int ch = i * 256 + tid, row = ch >> 3, kc = ch & 7;
        ra[i] = *(const short8_t*)(gkvb + (size_t)bh * 4096 + row * 64 + kc * 8);
    }
#pragma unroll
    for (int i = 0; i < 8; ++i) {
        int ch = i * 256 + tid, row = ch >> 3, kc = ch & 7;
        rb[i] = *(const short8_t*)(wpT + (size_t)(c0 + row) * 768 + h * 64 + kc * 8);
    }
#pragma unroll
    for (int i = 0; i < 2; ++i) {
        int ch = i * 256 + tid, row = ch >> 3, kc = ch & 7;
        *(short8_t*)(As + row * 64 + ((kc ^ (row & 7)) * 8)) = ra[i];
    }
#pragma unroll
    for (int i = 0; i < 8; ++i) {
        int ch = i * 256 + tid, row = ch >> 3, kc = ch & 7;
        *(short8_t*)(Bs + row * 64 + ((kc ^ (row & 7)) * 8)) = rb[i];
    }
    __syncthreads();

    f32x4_t acc[4][4] = {};
#pragma unroll
    for (int ks = 0; ks < 2; ++ks) {
        short8_t a[4], bfr[4];
#pragma unroll
        for (int mi = 0; mi < 4; ++mi) {
            int row = mi * 16 + lr;
            a[mi] = *(const short8_t*)(As + row * 64 + (((ks * 4 + lg) ^ (row & 7)) * 8));
        }
#pragma unroll
        for (int nj = 0; nj < 4; ++nj) {
            int row = w * 64 + nj * 16 + lr;
            bfr[nj] = *(const short8_t*)(Bs + row * 64 + (((ks * 4 + lg) ^ (row & 7)) * 8));
        }
#pragma unroll
        for (int mi = 0; mi < 4; ++mi)
#pragma unroll
            for (int nj = 0; nj < 4; ++nj)
                acc[mi][nj] = __builtin_amdgcn_mfma_f32_16x16x32_bf16(a[mi], bfr[nj], acc[mi][nj], 0, 0, 0);
    }
    __syncthreads();

#pragma unroll
    for (int mi = 0; mi < 4; ++mi)
#pragma unroll
        for (int nj = 0; nj < 4; ++nj) {
            unsigned int w0 = (unsigned int)to_bf16(acc[mi][nj][0]) |
                              ((unsigned int)to_bf16(acc[mi][nj][1]) << 16);
            unsigned int w1 = (unsigned int)to_bf16(acc[mi][nj][2]) |
                              ((unsigned int)to_bf16(acc[mi][nj][3]) << 16);
            uint2 pk; pk.x = w0; pk.y = w1;
            *(uint2*)(Bs + (w * 64 + nj * 16 + lr) * 64 + mi * 16 + lg * 4) = pk;
        }
    __syncthreads();
#pragma unroll
    for (int i = 0; i < 8; ++i) {
        int ch = i * 256 + tid, cl = ch >> 3, dk = ch & 7;
        short8_t v = *(const short8_t*)(Bs + cl * 64 + dk * 8);
        *(short8_t*)(MT + ((size_t)(b * 768) + c0 + cl) * 768 + h * 64 + dk * 8) = v;
    }
}

extern "C" void kernel_launch(void* const* d_in, const int* in_sizes, int n_in,
                              void* d_out, int out_size, void* d_ws, size_t ws_size,
                              hipStream_t stream) {
    const float* x      = (const float*)d_in[0];
    const float* w_qkv  = (const float*)d_in[1];
    const float* w_proj = (const float*)d_in[2];
    const float* b_proj = (const float*)d_in[3];
    float* out = (float*)d_out;
    char* ws = (char*)d_ws;

    unsigned short* qkv_bf = (unsigned short*)(ws);               // 65536*2304*2 = 301,989,888
    unsigned short* wqkvT  = (unsigned short*)(ws + 301989888);   // 2304*768*2   =   3,538,944
    float*          part   = (float*)(ws + 305528832);            // 1536*4096*4  =  25,165,824
    unsigned short* MT     = (unsigned short*)(ws + 330694656);   // 16*768*768*2 =  18,874,368
    unsigned short* xb   = (unsigned short*)d_out;                          // 100.7 MB
    unsigned short* gkvb = (unsigned short*)((char*)d_out + 134217728);     // 1.57 MB
    unsigned short* wpT  = (unsigned short*)((char*)d_out + 136314880);     // 1.18 MB

    k_cvt_bf16<<<2048, 256, 0, stream>>>(x, xb, 50331648L);
    k_wqkvT<<<864, 256, 0, stream>>>(w_qkv, wqkvT);
    k_wprojT<<<288, 256, 0, stream>>>(w_proj, wpT);
    k_gemm256<true, false, true, false><<<2304, 512, 0, stream>>>(
        xb, 768, wqkvT, 768, qkv_bf, 2304, nullptr, 9, 768);
    k_kvpart<<<1536, 256, 0, stream>>>(qkv_bf, part);
    k_gkv<<<192, 256, 0, stream>>>(part, gkvb);
    k_M<<<576, 256, 0, stream>>>(gkvb, wpT, MT);
    k_gemm256<false, true, false, true><<<768, 512, 0, stream>>>(
        qkv_bf, 2304, MT, 768, out, 768, b_proj, 3, 768);
}

// Round 6
// 499.301 us; speedup vs baseline: 2.0890x; 1.0135x over previous
//
#include <hip/hip_runtime.h>
#include <hip/hip_bf16.h>

// Problem: B=16, N=4096, C=768, H=12, D=64
// x[16,4096,768] f32; w_qkv[768,2304] f32; w_proj[768,768] f32; b_proj[768] f32
// out[16,4096,768] f32

typedef __attribute__((ext_vector_type(8))) short short8_t;
typedef __attribute__((ext_vector_type(4))) float f32x4_t;

typedef __attribute__((address_space(1))) void as1_void;
typedef __attribute__((address_space(3))) void as3_void;

__device__ __forceinline__ void gload_lds16(const void* g, void* l) {
    __builtin_amdgcn_global_load_lds(
        (as1_void*)(unsigned long long)(g),
        (as3_void*)(unsigned long long)(l), 16, 0, 0);
}

__device__ __forceinline__ float gelu_exact(float x) {
    return 0.5f * x * (1.0f + erff(x * 0.7071067811865475f));
}

__device__ __forceinline__ unsigned short to_bf16(float f) {
    __hip_bfloat16 h = __float2bfloat16(f);
    return *reinterpret_cast<unsigned short*>(&h);
}

__device__ __forceinline__ f32x4_t mfma16(short8_t a, short8_t b, f32x4_t c) {
    return __builtin_amdgcn_mfma_f32_16x16x32_bf16(a, b, c, 0, 0, 0);
}

// ---------------- f32 -> bf16 convert (vectorized) ----------------
__global__ __launch_bounds__(256) void k_cvt_bf16(const float* __restrict__ in,
                                                  unsigned short* __restrict__ out,
                                                  long n) {
    long i = (long)blockIdx.x * blockDim.x + threadIdx.x;
    long stride = (long)gridDim.x * blockDim.x;
    for (long idx = i * 4; idx < n; idx += stride * 4) {
        float4 v = *(const float4*)(in + idx);
        ushort4 o;
        o.x = to_bf16(v.x); o.y = to_bf16(v.y); o.z = to_bf16(v.z); o.w = to_bf16(v.w);
        *(ushort4*)(out + idx) = o;
    }
}

// ---------------- transpose+convert w_qkv [768][2304] -> [2304][768] bf16 ----------------
__global__ __launch_bounds__(256) void k_wqkvT(const float* __restrict__ w,
                                               unsigned short* __restrict__ wT) {
    int gid = blockIdx.x * 256 + threadIdx.x;       // 2304 * 96
    int c = gid / 96, rblk = gid % 96;
    int r0 = rblk * 8;
    short8_t o;
#pragma unroll
    for (int i = 0; i < 8; ++i)
        o[i] = (short)to_bf16(w[(size_t)(r0 + i) * 2304 + c]);
    *(short8_t*)(wT + (size_t)c * 768 + r0) = o;
}

// ---------------- transpose+convert w_proj [768][768] -> wpT[c][r] bf16 ----------------
__global__ __launch_bounds__(256) void k_wprojT(const float* __restrict__ w,
                                                unsigned short* __restrict__ wT) {
    int gid = blockIdx.x * 256 + threadIdx.x;       // 768 * 96
    int c = gid / 96, rblk = gid % 96;
    int r0 = rblk * 8;
    short8_t o;
#pragma unroll
    for (int i = 0; i < 8; ++i)
        o[i] = (short)to_bf16(w[(size_t)(r0 + i) * 768 + c]);
    *(short8_t*)(wT + (size_t)c * 768 + r0) = o;
}

// ================= 256x256 8-phase GEMM with register prefetch =================
// Frags for phase p are ds_read at phase p-1 AFTER its MFMA cluster; the LDS
// drain overlaps MFMA + barrier window; lgkmcnt(0) gate at p is ~free.
// vmcnt(4) at q3/q7 guarantees every slot read at p landed by p's barrier.
template<bool GELU_EPI, bool BATCHED_B, bool BF16_OUT, bool BIAS>
__global__ __launch_bounds__(512, 2)
void k_gemm256(const unsigned short* __restrict__ A, int lda,
               const unsigned short* __restrict__ Bt, int ldb,
               void* __restrict__ Cout, int ldc,
               const float* __restrict__ bias,
               int tiles_n, int K) {
    __shared__ __attribute__((aligned(16))) unsigned short lds[2][2][2][128 * 64];

    const int nwg = gridDim.x;
    int bid = blockIdx.x;
    bid = (bid & 7) * (nwg >> 3) + (bid >> 3);

    const int tn = bid % tiles_n, tm = bid / tiles_n;
    const int row0 = tm * 256, col0 = tn * 256;

    const unsigned short* Bb = Bt;
    if (BATCHED_B) Bb += (size_t)(row0 >> 12) * 768 * 768;

    const int tid = threadIdx.x;
    const int lane = tid & 63;
    const int w = tid >> 6;
    const int wm = w >> 2;
    const int wn = w & 3;
    const int lr = lane & 15, lg = lane >> 4;

    const int c0 = tid, c1 = 512 + tid;
    const int sr0 = c0 >> 3, sk0 = (c0 & 7) ^ (sr0 & 7);
    const int sr1 = c1 >> 3, sk1 = (c1 & 7) ^ (sr1 & 7);

    auto stageA = [&](int buf, int half, int kt) {
        const unsigned short* base = A + (size_t)(row0 + half * 128) * lda + kt * 64;
        gload_lds16(base + (size_t)sr0 * lda + sk0 * 8, &lds[0][buf][half][c0 * 8]);
        gload_lds16(base + (size_t)sr1 * lda + sk1 * 8, &lds[0][buf][half][c1 * 8]);
    };
    auto stageB = [&](int buf, int half, int kt) {
        const unsigned short* base = Bb + (size_t)(col0 + half * 128) * ldb + kt * 64;
        gload_lds16(base + (size_t)sr0 * ldb + sk0 * 8, &lds[1][buf][half][c0 * 8]);
        gload_lds16(base + (size_t)sr1 * ldb + sk1 * 8, &lds[1][buf][half][c1 * 8]);
    };
    auto ldA = [&](int buf, int mi, int ks) -> short8_t {
        int row = mi * 16 + lr;
        int kc = (ks * 4 + lg) ^ (row & 7);
        return *(const short8_t*)&lds[0][buf][wm][row * 64 + kc * 8];
    };
    auto ldB = [&](int buf, int nj, int ks) -> short8_t {
        int row = wn * 64 + nj * 16 + lr;
        int half = row >> 7, rl = row & 127;
        int kc = (ks * 4 + lg) ^ (rl & 7);
        return *(const short8_t*)&lds[1][buf][half][rl * 64 + kc * 8];
    };

    f32x4_t acc[8][4] = {};
    short8_t bfrag[4][2];     // B-frags of current buf, reloaded at q3/q7 post-MFMA
    short8_t afrP[2][4];      // double-buffered A-pair: [parity][mi_in_pair*2+ks]

#define FENCE asm volatile("" ::: "memory")
// PH(q, STAGE, VM, nbuf, nq): MFMA with afrP[q&1]+bfrag (pre-read), then read
// next phase's frags: A-pair (2*nq,2*nq+1) of nbuf into afrP[(q+1)&1]; at q==3
// also reload all 8 bfrag from nbuf (WAR on bfrag orders them after MFMA).
#define PH(q, STAGE_STMT, VM_STMT, nbuf, nq)                                    \
    {                                                                           \
        STAGE_STMT;                                                             \
        VM_STMT;                                                                \
        FENCE;                                                                  \
        __builtin_amdgcn_s_barrier();                                           \
        FENCE;                                                                  \
        asm volatile("s_waitcnt lgkmcnt(0)" ::: "memory");                      \
        __builtin_amdgcn_sched_barrier(0);                                      \
        __builtin_amdgcn_s_setprio(1);                                          \
        _Pragma("unroll") for (int nj = 0; nj < 4; ++nj) {                      \
            acc[2 * (q)][nj]     = mfma16(afrP[(q) & 1][0], bfrag[nj][0], acc[2 * (q)][nj]);     \
            acc[2 * (q)][nj]     = mfma16(afrP[(q) & 1][1], bfrag[nj][1], acc[2 * (q)][nj]);     \
            acc[2 * (q) + 1][nj] = mfma16(afrP[(q) & 1][2], bfrag[nj][0], acc[2 * (q) + 1][nj]); \
            acc[2 * (q) + 1][nj] = mfma16(afrP[(q) & 1][3], bfrag[nj][1], acc[2 * (q) + 1][nj]); \
        }                                                                       \
        __builtin_amdgcn_s_setprio(0);                                          \
        if ((q) == 3) {                                                         \
            _Pragma("unroll") for (int nj = 0; nj < 4; ++nj)                    \
                _Pragma("unroll") for (int ks = 0; ks < 2; ++ks)                \
                    bfrag[nj][ks] = ldB(nbuf, nj, ks);                          \
        }                                                                       \
        afrP[((q) + 1) & 1][0] = ldA(nbuf, 2 * (nq), 0);                        \
        afrP[((q) + 1) & 1][1] = ldA(nbuf, 2 * (nq), 1);                        \
        afrP[((q) + 1) & 1][2] = ldA(nbuf, 2 * (nq) + 1, 0);                    \
        afrP[((q) + 1) & 1][3] = ldA(nbuf, 2 * (nq) + 1, 1);                    \
        FENCE;                                                                  \
        __builtin_amdgcn_s_barrier();                                           \
        FENCE;                                                                  \
    }

    const int nt = K >> 6;          // 12 for K=768
    const int niter = nt >> 1;

    // prologue: tile0 full into buf0; drain; tile1's B0,B1,A-h0 into buf1 (6 outstanding)
    stageA(0, 0, 0); stageA(0, 1, 0); stageB(0, 0, 0); stageB(0, 1, 0);
    asm volatile("s_waitcnt vmcnt(0)" ::: "memory");
    stageB(1, 0, 1); stageB(1, 1, 1); stageA(1, 0, 1);
    __builtin_amdgcn_s_barrier();
    FENCE;
    // pre-read q0's frags (buf0 fully landed)
#pragma unroll
    for (int nj = 0; nj < 4; ++nj)
#pragma unroll
        for (int ks = 0; ks < 2; ++ks)
            bfrag[nj][ks] = ldB(0, nj, ks);
    afrP[0][0] = ldA(0, 0, 0); afrP[0][1] = ldA(0, 0, 1);
    afrP[0][2] = ldA(0, 1, 0); afrP[0][3] = ldA(0, 1, 1);
    FENCE;

    for (int it = 0; it < niter; ++it) {
        const int t1 = 2 * it + 1;
        const int tA = (2 * it + 2 < nt) ? 2 * it + 2 : 0;
        const int tB = (2 * it + 3 < nt) ? 2 * it + 3 : 0;
        // q0-q3: compute tile 2it from buf0 (frags prefetched)
        PH(0, stageA(1, 1, t1), (void)0, 0, 1);
        PH(1, stageB(0, 0, tA), (void)0, 0, 2);
        PH(2, stageB(0, 1, tA), (void)0, 0, 3);
        PH(3, stageA(0, 0, tA), asm volatile("s_waitcnt vmcnt(4)" ::: "memory"), 1, 0);
        // q4-q7: compute tile 2it+1 from buf1
        PH(0, stageA(0, 1, tA), (void)0, 1, 1);
        PH(1, stageB(1, 0, tB), (void)0, 1, 2);
        PH(2, stageB(1, 1, tB), (void)0, 1, 3);
        PH(3, stageA(1, 0, tB), asm volatile("s_waitcnt vmcnt(4)" ::: "memory"), 0, 0);
    }
    asm volatile("s_waitcnt vmcnt(0)" ::: "memory");
#undef PH
#undef FENCE

    const int rbase = row0 + wm * 128 + (lg << 2);
    const int cbase = col0 + wn * 64 + lr;
#pragma unroll
    for (int mi = 0; mi < 8; ++mi)
#pragma unroll
        for (int nj = 0; nj < 4; ++nj)
#pragma unroll
            for (int r = 0; r < 4; ++r) {
                int row = rbase + mi * 16 + r;
                int col = cbase + nj * 16;
                float v = acc[mi][nj][r];
                if (GELU_EPI) { if (col < 768) v = gelu_exact(v); }
                if (BIAS) v += bias[col];
                if (BF16_OUT)
                    ((unsigned short*)Cout)[(size_t)row * ldc + col] = to_bf16(v);
                else
                    ((float*)Cout)[(size_t)row * ldc + col] = v;
            }
}

// ---------------- kv partials: part[ch*192+bh][d][e] = sum_{n in chunk} k[n,d]*v[n,e] ----------------
__global__ __launch_bounds__(256) void k_kvpart(const unsigned short* __restrict__ qkv,
                                                float* __restrict__ part) {
    const int bid = blockIdx.x;
    const int ch = bid / 192, bh = bid % 192;
    const int b = bh / 12, h = bh % 12;
    const size_t rowbase = (size_t)b * 4096 + (size_t)ch * 512;
    const unsigned short* kptr = qkv + 768 + h * 64;
    const unsigned short* vptr = qkv + 1536 + h * 64;

    __shared__ __attribute__((aligned(16))) unsigned short kT[64 * 64];
    __shared__ __attribute__((aligned(16))) unsigned short vT[64 * 64];

    const int tid = threadIdx.x, lane = tid & 63, w = tid >> 6;
    const int np = tid >> 3;
    const int g = tid & 7;

    f32x4_t acc[4] = {};

    for (int it = 0; it < 8; ++it) {
        const size_t r0 = (rowbase + it * 64 + 2 * np) * 2304;
        short8_t k0 = *(const short8_t*)(kptr + r0 + g * 8);
        short8_t k1 = *(const short8_t*)(kptr + r0 + 2304 + g * 8);
        short8_t v0 = *(const short8_t*)(vptr + r0 + g * 8);
        short8_t v1 = *(const short8_t*)(vptr + r0 + 2304 + g * 8);
        __syncthreads();
#pragma unroll
        for (int j = 0; j < 8; ++j) {
            const int d = g * 8 + j;
            const int e = d * 64 + ((2 * np) ^ (((d ^ (d >> 3)) & 7) << 3));
            *(unsigned int*)(kT + e) =
                (unsigned int)(unsigned short)k0[j] | ((unsigned int)(unsigned short)k1[j] << 16);
            *(unsigned int*)(vT + e) =
                (unsigned int)(unsigned short)v0[j] | ((unsigned int)(unsigned short)v1[j] << 16);
        }
        __syncthreads();
        const int lr = lane & 15, lg = lane >> 4;
#pragma unroll
        for (int ks = 0; ks < 2; ++ks) {
            const int d = w * 16 + lr;
            short8_t a = *(const short8_t*)(kT + d * 64 +
                (((ks * 4 + lg) ^ ((d ^ (d >> 3)) & 7)) << 3));
#pragma unroll
            for (int nj = 0; nj < 4; ++nj) {
                const int e2 = nj * 16 + lr;
                short8_t bf = *(const short8_t*)(vT + e2 * 64 +
                    (((ks * 4 + lg) ^ ((e2 ^ (e2 >> 3)) & 7)) << 3));
                acc[nj] = __builtin_amdgcn_mfma_f32_16x16x32_bf16(a, bf, acc[nj], 0, 0, 0);
            }
        }
    }

    float* pout = part + (size_t)bid * 4096;
    const int rb = w * 16 + ((lane >> 4) << 2);
    const int cb = lane & 15;
#pragma unroll
    for (int nj = 0; nj < 4; ++nj)
#pragma unroll
        for (int r = 0; r < 4; ++r)
            pout[(rb + r) * 64 + nj * 16 + cb] = acc[nj][r];
}

// ---------------- reduce partials + scale + gelu -> gkvb bf16 [bh][64][64] ----------------
__global__ __launch_bounds__(256) void k_gkv(const float* __restrict__ part,
                                             unsigned short* __restrict__ gkvb) {
    const int bh = blockIdx.x;           // 0..191
    const int tid = threadIdx.x;
    const float* p0 = part + (size_t)bh * 4096 + tid * 16;
    float f[16];
#pragma unroll
    for (int j = 0; j < 16; ++j) f[j] = 0.f;
#pragma unroll
    for (int ch = 0; ch < 8; ++ch) {
        const float* p = p0 + (size_t)ch * 192 * 4096;
#pragma unroll
        for (int j4 = 0; j4 < 4; ++j4) {
            float4 v = *(const float4*)(p + j4 * 4);
            f[j4 * 4 + 0] += v.x; f[j4 * 4 + 1] += v.y;
            f[j4 * 4 + 2] += v.z; f[j4 * 4 + 3] += v.w;
        }
    }
    short8_t o0, o1;
#pragma unroll
    for (int j = 0; j < 8; ++j) {
        o0[j] = (short)to_bf16(gelu_exact(f[j] * 0.125f));
        o1[j] = (short)to_bf16(gelu_exact(f[8 + j] * 0.125f));
    }
    unsigned short* dst = gkvb + (size_t)bh * 4096 + tid * 16;
    *(short8_t*)(dst) = o0;
    *(short8_t*)(dst + 8) = o1;
}

// ---------------- M[d][c] = sum_e gkv[d][e]*wproj[h*64+e][c], stored as MT[b][c][hd] bf16 ----------------
__global__ __launch_bounds__(256) void k_M(const unsigned short* __restrict__ gkvb,
                                           const unsigned short* __restrict__ wpT,
                                           unsigned short* __restrict__ MT) {
    __shared__ __attribute__((aligned(16))) unsigned short As[64 * 64];
    __shared__ __attribute__((aligned(16))) unsigned short Bs[256 * 64];

    const int bid = blockIdx.x;
    const int bh = bid / 3, ct = bid % 3;
    const int b = bh / 12, h = bh % 12;
    const int c0 = ct * 256;
    const int tid = threadIdx.x, lane = tid & 63, w = tid >> 6;
    const int lr = lane & 15, lg = lane >> 4;

    short8_t ra[2], rb[8];
#pragma unroll
    for (int i = 0; i < 2; ++i) {
        int ch = i * 256 + tid, row = ch >> 3, kc = ch & 7;
        ra[i] = *(const short8_t*)(gkvb + (size_t)bh * 4096 + row * 64 + kc * 8);
    }
#pragma unroll
    for (int i = 0; i < 8; ++i) {
        int ch = i * 256 + tid, row = ch >> 3, kc = ch & 7;
        rb[i] = *(const short8_t*)(wpT + (size_t)(c0 + row) * 768 + h * 64 + kc * 8);
    }
#pragma unroll
    for (int i = 0; i < 2; ++i) {
        int ch = i * 256 + tid, row = ch >> 3, kc = ch & 7;
        *(short8_t*)(As + row * 64 + ((kc ^ (row & 7)) * 8)) = ra[i];
    }
#pragma unroll
    for (int i = 0; i < 8; ++i) {
        int ch = i * 256 + tid, row = ch >> 3, kc = ch & 7;
        *(short8_t*)(Bs + row * 64 + ((kc ^ (row & 7)) * 8)) = rb[i];
    }
    __syncthreads();

    f32x4_t acc[4][4] = {};
#pragma unroll
    for (int ks = 0; ks < 2; ++ks) {
        short8_t a[4], bfr[4];
#pragma unroll
        for (int mi = 0; mi < 4; ++mi) {
            int row = mi * 16 + lr;
            a[mi] = *(const short8_t*)(As + row * 64 + (((ks * 4 + lg) ^ (row & 7)) * 8));
        }
#pragma unroll
        for (int nj = 0; nj < 4; ++nj) {
            int row = w * 64 + nj * 16 + lr;
            bfr[nj] = *(const short8_t*)(Bs + row * 64 + (((ks * 4 + lg) ^ (row & 7)) * 8));
        }
#pragma unroll
        for (int mi = 0; mi < 4; ++mi)
#pragma unroll
            for (int nj = 0; nj < 4; ++nj)
                acc[mi][nj] = __builtin_amdgcn_mfma_f32_16x16x32_bf16(a[mi], bfr[nj], acc[mi][nj], 0, 0, 0);
    }
    __syncthreads();

#pragma unroll
    for (int mi = 0; mi < 4; ++mi)
#pragma unroll
        for (int nj = 0; nj < 4; ++nj) {
            unsigned int w0 = (unsigned int)to_bf16(acc[mi][nj][0]) |
                              ((unsigned int)to_bf16(acc[mi][nj][1]) << 16);
            unsigned int w1 = (unsigned int)to_bf16(acc[mi][nj][2]) |
                              ((unsigned int)to_bf16(acc[mi][nj][3]) << 16);
            uint2 pk; pk.x = w0; pk.y = w1;
            *(uint2*)(Bs + (w * 64 + nj * 16 + lr) * 64 + mi * 16 + lg * 4) = pk;
        }
    __syncthreads();
#pragma unroll
    for (int i = 0; i < 8; ++i) {
        int ch = i * 256 + tid, cl = ch >> 3, dk = ch & 7;
        short8_t v = *(const short8_t*)(Bs + cl * 64 + dk * 8);
        *(short8_t*)(MT + ((size_t)(b * 768) + c0 + cl) * 768 + h * 64 + dk * 8) = v;
    }
}

extern "C" void kernel_launch(void* const* d_in, const int* in_sizes, int n_in,
                              void* d_out, int out_size, void* d_ws, size_t ws_size,
                              hipStream_t stream) {
    const float* x      = (const float*)d_in[0];
    const float* w_qkv  = (const float*)d_in[1];
    const float* w_proj = (const float*)d_in[2];
    const float* b_proj = (const float*)d_in[3];
    float* out = (float*)d_out;
    char* ws = (char*)d_ws;

    unsigned short* qkv_bf = (unsigned short*)(ws);               // 65536*2304*2 = 301,989,888
    unsigned short* wqkvT  = (unsigned short*)(ws + 301989888);   // 2304*768*2   =   3,538,944
    float*          part   = (float*)(ws + 305528832);            // 1536*4096*4  =  25,165,824
    unsigned short* MT     = (unsigned short*)(ws + 330694656);   // 16*768*768*2 =  18,874,368
    unsigned short* xb   = (unsigned short*)d_out;                          // 100.7 MB
    unsigned short* gkvb = (unsigned short*)((char*)d_out + 134217728);     // 1.57 MB
    unsigned short* wpT  = (unsigned short*)((char*)d_out + 136314880);     // 1.18 MB

    k_cvt_bf16<<<2048, 256, 0, stream>>>(x, xb, 50331648L);
    k_wqkvT<<<864, 256, 0, stream>>>(w_qkv, wqkvT);
    k_wprojT<<<288, 256, 0, stream>>>(w_proj, wpT);
    k_gemm256<true, false, true, false><<<2304, 512, 0, stream>>>(
        xb, 768, wqkvT, 768, qkv_bf, 2304, nullptr, 9, 768);
    k_kvpart<<<1536, 256, 0, stream>>>(qkv_bf, part);
    k_gkv<<<192, 256, 0, stream>>>(part, gkvb);
    k_M<<<576, 256, 0, stream>>>(gkvb, wpT, MT);
    k_gemm256<false, true, false, true><<<768, 512, 0, stream>>>(
        qkv_bf, 2304, MT, 768, out, 768, b_proj, 3, 768);
}